// Round 11
// baseline (3663.941 us; speedup 1.0000x reference)
//
#include <hip/hip_runtime.h>
#include <math.h>

// ---------------- wavelet filter constants (orthogonal, L=12) ----------------
#define W0f  (-0.00107730108499558f)
#define W1f  (0.004777257511010651f)
#define W2f  (0.0005538422009938016f)
#define W3f  (-0.031582039318031156f)
#define W4f  (0.02752286553001629f)
#define W5f  (0.09750160558707936f)
#define W6f  (-0.12976686756709563f)
#define W7f  (-0.22626469396516913f)
#define W8f  (0.3152503517092432f)
#define W9f  (0.7511339080215775f)
#define W10f (0.4946238903983854f)
#define W11f (0.11154074335008017f)

__constant__ float cKA0[12] = {W11f,W10f,W9f,W8f,W7f,W6f,W5f,W4f,W3f,W2f,W1f,W0f};
__constant__ float cKA1[12] = {W0f,-W1f,W2f,-W3f,W4f,-W5f,W6f,-W7f,W8f,-W9f,W10f,-W11f};
__constant__ float cKS0[12] = {W0f,W1f,W2f,W3f,W4f,W5f,W6f,W7f,W8f,W9f,W10f,W11f};
__constant__ float cKS1[12] = {-W11f,W10f,-W9f,W8f,-W7f,W6f,-W5f,W4f,-W3f,W2f,-W1f,W0f};

// problem-size constants
#define S1c 134
#define S2c 72
#define S3c 41
#define A3c 1681
#define N1c 4596736UL
#define N2c 1327104UL
#define N3c 430336UL
#define PLc 2480128UL
#define NBLK 1024

// fast erf (Abramowitz-Stegun 7.1.26, max abs err 1.5e-7)
__device__ __forceinline__ float gelu_f(float x) {
    float z  = x * 0.70710678118654752440f;
    float az = fabsf(z);
    float t  = __builtin_amdgcn_rcpf(1.0f + 0.3275911f * az);
    float p  = t * (0.254829592f + t * (-0.284496736f + t * (1.421413741f +
               t * (-1.453152027f + t * 1.061405429f))));
    float e  = __expf(-az * az);
    float er = copysignf(1.0f - p * e, z);
    return 0.5f * x * (1.0f + er);
}

__device__ __forceinline__ int xcd_swizzle() {
    int bid = blockIdx.x;
    return (bid & 7) * ((int)gridDim.x >> 3) + (bid >> 3);
}

// lightweight device-scope grid barrier (sense-free, generation counter)
__device__ __forceinline__ void grid_barrier(unsigned* cnt, unsigned* gen, unsigned nb) {
    __syncthreads();
    if (threadIdx.x == 0) {
        unsigned g = __hip_atomic_load(gen, __ATOMIC_RELAXED, __HIP_MEMORY_SCOPE_AGENT);
        if (__hip_atomic_fetch_add(cnt, 1u, __ATOMIC_ACQ_REL, __HIP_MEMORY_SCOPE_AGENT) == nb - 1) {
            __hip_atomic_store(cnt, 0u, __ATOMIC_RELAXED, __HIP_MEMORY_SCOPE_AGENT);
            __hip_atomic_store(gen, g + 1u, __ATOMIC_RELEASE, __HIP_MEMORY_SCOPE_AGENT);
        } else {
            while (__hip_atomic_load(gen, __ATOMIC_ACQUIRE, __HIP_MEMORY_SCOPE_AGENT) == g) {
                __builtin_amdgcn_s_sleep(32);
            }
        }
    }
    __syncthreads();
}

// ================= device bodies =================

// smem: sIn 42x45 @0, rlo 42x17 @1890, rhi 42x17 @2604 -> 3318 floats
__device__ __forceinline__ void dwt_body(
    const float* __restrict__ in, float* __restrict__ ll, float* __restrict__ lh,
    float* __restrict__ hl, float* __restrict__ hh,
    int H, int W, int Ho, int Wo, int tilesX, int wg, float* smem) {
    float (*sIn)[45] = (float(*)[45])smem;
    float (*rlo)[17] = (float(*)[17])(smem + 1890);
    float (*rhi)[17] = (float(*)[17])(smem + 2604);
    int tpc = tilesX * tilesX;
    int c   = wg / tpc, rem = wg % tpc;
    int ty0 = (rem / tilesX) * 16;
    int tx0 = (rem % tilesX) * 16;
    const float* img = in + (size_t)c * H * W;
    int tid = threadIdx.x;
    for (int idx = tid; idx < 42 * 42; idx += 256) {
        int r = idx / 42, q = idx % 42;
        int gy = 2 * ty0 - 10 + r;
        int gx = 2 * tx0 - 10 + q;
        gy = gy < 0 ? -1 - gy : (gy >= H ? 2 * H - 1 - gy : gy);
        gx = gx < 0 ? -1 - gx : (gx >= W ? 2 * W - 1 - gx : gx);
        sIn[r][q] = img[gy * W + gx];
    }
    __syncthreads();
    for (int idx = tid; idx < 42 * 16; idx += 256) {
        int r = idx / 16, j = idx % 16;
        float alo = 0.f, ahi = 0.f;
        #pragma unroll
        for (int t = 0; t < 12; t++) {
            float v = sIn[r][2 * j + t];
            alo += v * cKA0[t];
            ahi += v * cKA1[t];
        }
        rlo[r][j] = alo; rhi[r][j] = ahi;
    }
    __syncthreads();
    int jy = tid / 16, jx = tid % 16;
    int oy = ty0 + jy, ox = tx0 + jx;
    if (oy < Ho && ox < Wo) {
        float a0 = 0.f, a1 = 0.f, a2 = 0.f, a3 = 0.f;
        #pragma unroll
        for (int t = 0; t < 12; t++) {
            float vl = rlo[2 * jy + t][jx];
            float vh = rhi[2 * jy + t][jx];
            a0 += vl * cKA0[t]; a1 += vl * cKA1[t];
            a2 += vh * cKA0[t]; a3 += vh * cKA1[t];
        }
        size_t o = (size_t)c * Ho * Wo + (size_t)oy * Wo + ox;
        ll[o] = a0; lh[o] = a1; hl[o] = a2; hh[o] = a3;
    }
}

// smem: sll/slh/shl/shh 21x22, sxl/sxh 32x22 -> 3256 floats
__device__ __forceinline__ void idwt_body(
    const float* __restrict__ ll, const float* __restrict__ lh,
    const float* __restrict__ hl, const float* __restrict__ hh,
    float* __restrict__ out, int h, int w, int Oh, int Ow, int tilesX,
    int wg, float* smem) {
    float (*sll)[22] = (float(*)[22])smem;
    float (*slh)[22] = (float(*)[22])(smem + 462);
    float (*shl)[22] = (float(*)[22])(smem + 924);
    float (*shh)[22] = (float(*)[22])(smem + 1386);
    float (*sxl)[22] = (float(*)[22])(smem + 1848);
    float (*sxh)[22] = (float(*)[22])(smem + 2552);
    int tpc = tilesX * tilesX;
    int c   = wg / tpc, rem = wg % tpc;
    int my0 = (rem / tilesX) * 16;
    int nx0 = (rem % tilesX) * 16;
    int tid = threadIdx.x;
    size_t cb = (size_t)c * h * w;
    for (int idx = tid; idx < 21 * 21; idx += 256) {
        int r = idx / 21, q = idx % 21;
        int gy = min(my0 + r, h - 1);
        int gx = min(nx0 + q, w - 1);
        size_t g = cb + (size_t)gy * w + gx;
        sll[r][q] = ll[g]; slh[r][q] = lh[g];
        shl[r][q] = hl[g]; shh[r][q] = hh[g];
    }
    __syncthreads();
    for (int idx = tid; idx < 32 * 21; idx += 256) {
        int r = idx / 21, q = idx % 21;
        int mp = r >> 1, p = r & 1;
        float al = 0.f, ah = 0.f;
        #pragma unroll
        for (int s = 0; s < 6; s++) {
            float k0 = cKS0[2 * s + 1 - p];
            float k1 = cKS1[2 * s + 1 - p];
            al += sll[mp + s][q] * k0 + slh[mp + s][q] * k1;
            ah += shl[mp + s][q] * k0 + shh[mp + s][q] * k1;
        }
        sxl[r][q] = al; sxh[r][q] = ah;
    }
    __syncthreads();
    for (int idx = tid; idx < 32 * 32; idx += 256) {
        int r = idx / 32, q2 = idx % 32;
        int np = q2 >> 1, q = q2 & 1;
        int oy = 2 * my0 + r, ox = 2 * nx0 + q2;
        if (oy < Oh && ox < Ow) {
            float a = 0.f;
            #pragma unroll
            for (int s = 0; s < 6; s++) {
                float k0 = cKS0[2 * s + 1 - q];
                float k1 = cKS1[2 * s + 1 - q];
                a += sxl[r][np + s] * k0 + sxh[r][np + s] * k1;
            }
            out[(size_t)c * Oh * Ow + (size_t)oy * Ow + ox] = a;
        }
    }
}

// smem: sw 1024 @0, sv 256 @1024
__device__ __forceinline__ void mix_body(
    float* __restrict__ ll3, float* __restrict__ lh3,
    float* __restrict__ lh2, float* __restrict__ lh1,
    const float* __restrict__ wl, int bid, float* smem) {
    float* sw = smem;
    float* sv = smem + 1024;
    const float* wll = wl;
    const float* wh1 = wl + A3c * 1024;
    const float* wh2 = wh1 + 3 * S1c * 1024;
    const float* wh3 = wh2 + 3 * S2c * 1024;
    int tid = threadIdx.x;
    if (bid < A3c) {
        const float* wb = wll + (size_t)bid * 1024;
        for (int k = tid; k < 1024; k += 256) sw[k] = wb[k];
        int b = tid >> 5, i = tid & 31;
        sv[tid] = ll3[((size_t)(b * 32 + i)) * A3c + bid];
        __syncthreads();
        float acc = 0.f;
        #pragma unroll
        for (int k = 0; k < 32; k++) acc += sv[b * 32 + k] * sw[k * 32 + i];
        ll3[((size_t)(b * 32 + i)) * A3c + bid] = acc;
        return;
    }
    int t = bid - A3c;
    float* hb; const float* wb; int Hs, Ws, s, y, xb; size_t bstride;
    if (t < 2 * S3c * 3) {
        Hs = Ws = S3c; bstride = N3c;
        int per = 2 * S3c; s = t / per; int r = t % per; y = r / 2; xb = r % 2;
        hb = lh3; wb = wh3;
    } else if ((t -= 2 * S3c * 3) < 3 * S2c * 3) {
        Hs = Ws = S2c; bstride = N2c;
        int per = 3 * S2c; s = t / per; int r = t % per; y = r / 3; xb = r % 3;
        hb = lh2; wb = wh2;
    } else {
        t -= 3 * S2c * 3;
        Hs = Ws = S1c; bstride = N1c;
        int per = 5 * S1c; s = t / per; int r = t % per; y = r / 5; xb = r % 5;
        hb = lh1; wb = wh1;
    }
    hb += (size_t)s * bstride;
    wb += ((size_t)s * Hs + y) * 1024;
    for (int k = tid; k < 1024; k += 256) sw[k] = wb[k];
    __syncthreads();
    int q = xb * 256 + tid;
    if (q < 8 * Ws) {
        int b = q / Ws, x = q % Ws;
        size_t base = ((size_t)(b * 32) * Hs + y) * Ws + x;
        size_t cs = (size_t)Hs * Ws;
        float acc[32];
        #pragma unroll
        for (int o = 0; o < 32; o++) acc[o] = 0.f;
        for (int i = 0; i < 32; i++) {
            float v = hb[base + (size_t)i * cs];
            #pragma unroll
            for (int o4 = 0; o4 < 8; o4++) {
                float4 w4 = *(const float4*)&sw[i * 32 + o4 * 4];
                acc[o4*4+0] += v * w4.x; acc[o4*4+1] += v * w4.y;
                acc[o4*4+2] += v * w4.z; acc[o4*4+3] += v * w4.w;
            }
        }
        #pragma unroll
        for (int o = 0; o < 32; o++) hb[base + (size_t)o * cs] = acc[o];
    }
}

// ================= persistent mid-layer: dwt2+dwt3+mix+idwt3+idwt2, 4 barriers =================
__global__ __launch_bounds__(256, 2) void mid_layer(
    float* b1, float* ll2, float* lh2, float* hl2, float* hh2,
    float* ll3, float* lh3, float* hl3, float* hh3, const float* wl,
    unsigned* cnt, unsigned* gen) {
    __shared__ float smem[3328];
    float* ll1 = b1;
    float* lh1 = b1 + N1c;
    for (int w = blockIdx.x; w < 6400; w += gridDim.x) {
        dwt_body(ll1, ll2, lh2, hl2, hh2, S1c, S1c, S2c, S2c, 5, w, smem);
        __syncthreads();
    }
    grid_barrier(cnt, gen, NBLK);
    for (int w = blockIdx.x; w < 2304; w += gridDim.x) {
        dwt_body(ll2, ll3, lh3, hl3, hh3, S2c, S2c, S3c, S3c, 3, w, smem);
        __syncthreads();
    }
    grid_barrier(cnt, gen, NBLK);
    for (int w = blockIdx.x; w < 4585; w += gridDim.x) {
        mix_body(ll3, lh3, lh2, lh1, wl, w, smem);
        __syncthreads();
    }
    grid_barrier(cnt, gen, NBLK);
    for (int w = blockIdx.x; w < 2304; w += gridDim.x) {
        idwt_body(ll3, lh3, hl3, hh3, ll2, S3c, S3c, S2c, S2c, 3, w, smem);
        __syncthreads();
    }
    grid_barrier(cnt, gen, NBLK);
    for (int w = blockIdx.x; w < 6400; w += gridDim.x) {
        idwt_body(ll2, lh2, hl2, hh2, ll1, S2c, S2c, S1c, S1c, 5, w, smem);
        __syncthreads();
    }
}

// ================= standalone kernels (L1 level) =================

__global__ __launch_bounds__(256) void dwt2d(
    const float* __restrict__ in, float* __restrict__ ll, float* __restrict__ lh,
    float* __restrict__ hl, float* __restrict__ hh, int H, int W, int Ho, int Wo,
    int tilesX) {
    __shared__ float smem[3328];
    dwt_body(in, ll, lh, hl, hh, H, W, Ho, Wo, tilesX, xcd_swizzle(), smem);
}

__global__ __launch_bounds__(256) void dwt2d_fc0(
    const float* __restrict__ u, const float* __restrict__ par,
    const float* __restrict__ xg, const float* __restrict__ yg,
    const float* __restrict__ fw, const float* __restrict__ fb,
    float* __restrict__ ll, float* __restrict__ lh,
    float* __restrict__ hl, float* __restrict__ hh) {
    const int Hd = 258, S = 256, Ho = S1c, Wo = S1c, tilesX = 9;
    int wg  = xcd_swizzle();
    int tpc = tilesX * tilesX;
    int c   = wg / tpc, rem = wg % tpc;
    int b   = c >> 5, o = c & 31;
    int ty0 = (rem / tilesX) * 16;
    int tx0 = (rem % tilesX) * 16;
    float w0 = fw[o*4], w1 = fw[o*4+1], w2 = fw[o*4+2], w3 = fw[o*4+3], bv = fb[o];
    __shared__ float sIn[42][45];
    __shared__ float rlo[42][17];
    __shared__ float rhi[42][17];
    int tid = threadIdx.x;
    for (int idx = tid; idx < 42 * 42; idx += 256) {
        int r = idx / 42, q = idx % 42;
        int gy = 2 * ty0 - 10 + r;
        int gx = 2 * tx0 - 10 + q;
        gy = gy < 0 ? -1 - gy : (gy >= Hd ? 2 * Hd - 1 - gy : gy);
        gx = gx < 0 ? -1 - gx : (gx >= Hd ? 2 * Hd - 1 - gx : gx);
        int iy = gy - 1; iy = iy < 0 ? -iy : (iy >= S ? 2 * S - 2 - iy : iy);
        int ix = gx - 1; ix = ix < 0 ? -ix : (ix >= S ? 2 * S - 2 - ix : ix);
        float vu = u  [(b * S + iy) * S + ix];
        float vp = par[(b * S + iy) * S + ix];
        sIn[r][q] = w0 * vu + w1 * vp + w2 * xg[b * S + iy] + w3 * yg[b * S + ix] + bv;
    }
    __syncthreads();
    for (int idx = tid; idx < 42 * 16; idx += 256) {
        int r = idx / 16, j = idx % 16;
        float alo = 0.f, ahi = 0.f;
        #pragma unroll
        for (int t = 0; t < 12; t++) {
            float v = sIn[r][2 * j + t];
            alo += v * cKA0[t];
            ahi += v * cKA1[t];
        }
        rlo[r][j] = alo; rhi[r][j] = ahi;
    }
    __syncthreads();
    int jy = tid / 16, jx = tid % 16;
    int oy = ty0 + jy, ox = tx0 + jx;
    if (oy < Ho && ox < Wo) {
        float a0 = 0.f, a1 = 0.f, a2 = 0.f, a3 = 0.f;
        #pragma unroll
        for (int t = 0; t < 12; t++) {
            float vl = rlo[2 * jy + t][jx];
            float vh = rhi[2 * jy + t][jx];
            a0 += vl * cKA0[t]; a1 += vl * cKA1[t];
            a2 += vh * cKA0[t]; a3 += vh * cKA1[t];
        }
        size_t oo = (size_t)c * Ho * Wo + (size_t)oy * Wo + ox;
        ll[oo] = a0; lh[oo] = a1; hl[oo] = a2; hh[oo] = a3;
    }
}

__global__ __launch_bounds__(256) void idwt2d(
    const float* __restrict__ ll, const float* __restrict__ lh,
    const float* __restrict__ hl, const float* __restrict__ hh,
    float* __restrict__ out, const float* __restrict__ pb,
    int h, int w, int Oh, int Ow, int do_gelu, int tilesX) {
    int wg  = xcd_swizzle();
    int tpc = tilesX * tilesX;
    int c   = wg / tpc, rem = wg % tpc;
    int my0 = (rem / tilesX) * 16;
    int nx0 = (rem % tilesX) * 16;
    __shared__ float sll[21][22], slh[21][22], shl[21][22], shh[21][22];
    __shared__ float sxl[32][22], sxh[32][22];
    int tid = threadIdx.x;
    size_t cb = (size_t)c * h * w;
    float bias = pb ? pb[c & 31] : 0.f;
    for (int idx = tid; idx < 21 * 21; idx += 256) {
        int r = idx / 21, q = idx % 21;
        int gy = min(my0 + r, h - 1);
        int gx = min(nx0 + q, w - 1);
        size_t g = cb + (size_t)gy * w + gx;
        sll[r][q] = ll[g]; slh[r][q] = lh[g];
        shl[r][q] = hl[g]; shh[r][q] = hh[g];
    }
    __syncthreads();
    for (int idx = tid; idx < 32 * 21; idx += 256) {
        int r = idx / 21, q = idx % 21;
        int mp = r >> 1, p = r & 1;
        float al = 0.f, ah = 0.f;
        #pragma unroll
        for (int s = 0; s < 6; s++) {
            float k0 = cKS0[2 * s + 1 - p];
            float k1 = cKS1[2 * s + 1 - p];
            al += sll[mp + s][q] * k0 + slh[mp + s][q] * k1;
            ah += shl[mp + s][q] * k0 + shh[mp + s][q] * k1;
        }
        sxl[r][q] = al; sxh[r][q] = ah;
    }
    __syncthreads();
    for (int idx = tid; idx < 32 * 32; idx += 256) {
        int r = idx / 32, q2 = idx % 32;
        int np = q2 >> 1, q = q2 & 1;
        int oy = 2 * my0 + r, ox = 2 * nx0 + q2;
        if (oy < Oh && ox < Ow) {
            float a = bias;
            #pragma unroll
            for (int s = 0; s < 6; s++) {
                float k0 = cKS0[2 * s + 1 - q];
                float k1 = cKS1[2 * s + 1 - q];
                a += sxl[r][np + s] * k0 + sxh[r][np + s] * k1;
            }
            if (do_gelu) a = gelu_f(a);
            out[(size_t)c * Oh * Ow + (size_t)oy * Ow + ox] = a;
        }
    }
}

// ---------------- transpose all 4 layers ----------------
__global__ __launch_bounds__(256) void transpose_all(
    const float* __restrict__ w, float* __restrict__ wT) {
    __shared__ float t[64][65];
    int l  = blockIdx.y >> 4;
    int by = (blockIdx.y & 15) * 64;
    int bx = blockIdx.x * 64;
    const float* wl = w  + (size_t)l * 4194304;
    float* wTl      = wT + (size_t)l * 4194304;
    int tid = threadIdx.x;
    for (int idx = tid; idx < 4096; idx += 256) {
        int r = idx >> 6, q = idx & 63;
        t[r][q] = wl[(size_t)(by + r) * 4096 + bx + q];
    }
    __syncthreads();
    for (int idx = tid; idx < 4096; idx += 256) {
        int r = idx >> 6, q = idx & 63;
        wTl[(size_t)(bx + r) * 1024 + by + q] = t[q][r];
    }
}

// ---------------- bilinear interp of weights for all 4 layers, + pw folded in ----------------
__global__ __launch_bounds__(256) void interp4(
    const float* __restrict__ wT, const float* __restrict__ pw,
    float* __restrict__ wout) {
    int l = blockIdx.y;
    const float* wTl = wT + (size_t)l * 4194304;
    const float* pwl = pw + (size_t)l * 1024;
    float* base = wout + (size_t)l * PLc;
    __shared__ float spw[1024];
    int tid = threadIdx.x;
    for (int k = tid; k < 1024; k += 256) spw[k] = pwl[(k & 31) * 32 + (k >> 5)];
    __syncthreads();
    int bId = blockIdx.x;
    float* dst; int Ho, Wo, p;
    if (bId < A3c)                          { dst = base;                                  Ho = S3c; Wo = S3c; p = bId; }
    else if (bId < A3c + 3 * S1c)           { dst = base + A3c * 1024;                     Ho = 3;   Wo = S1c; p = bId - A3c; }
    else if (bId < A3c + 3 * (S1c + S2c))   { dst = base + (A3c + 3 * S1c) * 1024;         Ho = 3;   Wo = S2c; p = bId - A3c - 3 * S1c; }
    else                                    { dst = base + (A3c + 3 * (S1c + S2c)) * 1024; Ho = 3;   Wo = S3c; p = bId - A3c - 3 * (S1c + S2c); }
    int y = p / Wo, x = p % Wo;
    float sy = fmaxf((y + 0.5f) * (64.0f / Ho) - 0.5f, 0.0f);
    int y0 = min((int)sy, 63), y1 = min(y0 + 1, 63);
    float ty = fminf(sy - (float)y0, 1.0f);
    float sx = fmaxf((x + 0.5f) * (64.0f / Wo) - 0.5f, 0.0f);
    int x0 = min((int)sx, 63), x1 = min(x0 + 1, 63);
    float tx = fminf(sx - (float)x0, 1.0f);
    float c00 = (1.f - ty) * (1.f - tx), c01 = (1.f - ty) * tx;
    float c10 = ty * (1.f - tx),         c11 = ty * tx;
    const float4* s00 = (const float4*)(wTl + (size_t)(y0 * 64 + x0) * 1024);
    const float4* s01 = (const float4*)(wTl + (size_t)(y0 * 64 + x1) * 1024);
    const float4* s10 = (const float4*)(wTl + (size_t)(y1 * 64 + x0) * 1024);
    const float4* s11 = (const float4*)(wTl + (size_t)(y1 * 64 + x1) * 1024);
    float4* op = (float4*)(dst + (size_t)p * 1024);
    int k = tid;
    float4 a = s00[k], b = s01[k], c = s10[k], d = s11[k];
    float4 pw4 = *(const float4*)&spw[k * 4];
    float4 r;
    r.x = c00*a.x + c01*b.x + c10*c.x + c11*d.x + pw4.x;
    r.y = c00*a.y + c01*b.y + c10*c.y + c11*d.y + pw4.y;
    r.z = c00*a.z + c01*b.z + c10*c.z + c11*d.z + pw4.z;
    r.w = c00*a.w + c01*b.w + c10*c.w + c11*d.w + pw4.w;
    op[k] = r;
}

// ---------------- head: crop + fc1 + gelu + fc2, 2 px/thread, LDS weights ----------------
__global__ __launch_bounds__(256) void head_k(
    const float* __restrict__ h, const float* __restrict__ w1, const float* __restrict__ b1,
    const float* __restrict__ w2, const float* __restrict__ b2, float* __restrict__ out) {
    __shared__ float sw1[4096];
    __shared__ float sb1[128];
    __shared__ float sw2[128];
    int tid = threadIdx.x;
    for (int k = tid; k < 4096; k += 256) sw1[k] = w1[k];
    if (tid < 128) { sb1[tid] = b1[tid]; sw2[tid] = w2[tid]; }
    __syncthreads();
    const int Hp = 258;
    const int QP = 262144;
    int g0 = blockIdx.x * 256 + tid;
    float in[2][32];
    #pragma unroll
    for (int p = 0; p < 2; p++) {
        int gid = g0 + p * QP;
        int b = gid >> 16, r = gid & 65535;
        int yy = r >> 8, xx = r & 255;
        size_t base = (size_t)b * 32 * Hp * Hp + (size_t)(yy + 1) * Hp + (xx + 1);
        #pragma unroll
        for (int i = 0; i < 32; i++) in[p][i] = h[base + (size_t)i * Hp * Hp];
    }
    float acc0 = 0.f, acc1 = 0.f;
    for (int j = 0; j < 128; j++) {
        float h0 = sb1[j], h1 = h0;
        #pragma unroll
        for (int i4 = 0; i4 < 8; i4++) {
            float4 wv = *(const float4*)&sw1[j * 32 + i4 * 4];
            h0 += wv.x * in[0][i4*4+0] + wv.y * in[0][i4*4+1] + wv.z * in[0][i4*4+2] + wv.w * in[0][i4*4+3];
            h1 += wv.x * in[1][i4*4+0] + wv.y * in[1][i4*4+1] + wv.z * in[1][i4*4+2] + wv.w * in[1][i4*4+3];
        }
        float w2j = sw2[j];
        acc0 += w2j * gelu_f(h0);
        acc1 += w2j * gelu_f(h1);
    }
    float b2v = b2[0];
    out[g0     ] = acc0 + b2v;
    out[g0 + QP] = acc1 + b2v;
}

extern "C" void kernel_launch(void* const* d_in, const int* in_sizes, int n_in,
                              void* d_out, int out_size, void* d_ws, size_t ws_size,
                              hipStream_t stream) {
    (void)in_sizes; (void)n_in; (void)out_size;
    const float* u    = (const float*)d_in[0];
    const float* par  = (const float*)d_in[1];
    const float* xg   = (const float*)d_in[2];
    const float* yg   = (const float*)d_in[3];
    const float* fc0w = (const float*)d_in[4];
    const float* fc0b = (const float*)d_in[5];
    const float* wcw  = (const float*)d_in[6];
    const float* pww  = (const float*)d_in[7];
    const float* pwb  = (const float*)d_in[8];
    const float* fc1w = (const float*)d_in[9];
    const float* fc1b = (const float*)d_in[10];
    const float* fc2w = (const float*)d_in[11];
    const float* fc2b = (const float*)d_in[12];
    float* out = (float*)d_out;
    float* ws  = (float*)d_ws;

    const int Hp = 258;
    const size_t HW = (size_t)Hp * Hp;
    const size_t NH = 256 * HW;
    const int S1 = S1c, S2 = S2c, S3 = S3c;
    const size_t N1 = N1c, N2 = N2c, N3 = N3c;

    float* H   = ws;
    float* b1  = H   + NH;      // ll1|lh1|hl1|hh1 contiguous (4*N1)
    float* ll2 = b1  + 4 * N1;
    float* lh2 = ll2 + N2;
    float* hl2 = lh2 + N2;
    float* hh2 = hl2 + N2;
    float* ll3 = hh2 + N2;
    float* lh3 = ll3 + N3;
    float* hl3 = lh3 + N3;
    float* hh3 = hl3 + N3;
    float* w4  = hh3 + N3;      // 4 layers x PLc interp'd weights
    unsigned* bar = (unsigned*)(w4 + 4 * PLc);   // barrier cnt/gen
    size_t needed = (size_t)((float*)bar + 16 - ws) * sizeof(float);
    if (ws_size < needed) return;
    float* wTall = b1 + N1;     // overlay lh1.. (dead until dwt L1 writes)

    // zero barrier state (deterministic per call; graph-capture legal)
    hipMemsetAsync((void*)bar, 0, 2 * sizeof(unsigned), stream);

    // ---- upfront weight prep ----
    transpose_all<<<dim3(64, 64), 256, 0, stream>>>(wcw, wTall);
    int nInterp = A3c + 3 * (S1 + S2 + S3);
    interp4<<<dim3(nInterp, 4), 256, 0, stream>>>(wTall, pww, w4);

    for (int l = 0; l < 4; l++) {
        const float* wl = w4 + (size_t)l * PLc;

        if (l == 0) {
            dwt2d_fc0<<<9 * 9 * 256, 256, 0, stream>>>(
                u, par, xg, yg, fc0w, fc0b, b1, b1 + N1, b1 + 2 * N1, b1 + 3 * N1);
        } else {
            dwt2d<<<9 * 9 * 256, 256, 0, stream>>>(
                H, b1, b1 + N1, b1 + 2 * N1, b1 + 3 * N1, Hp, Hp, S1, S1, 9);
        }

        mid_layer<<<NBLK, 256, 0, stream>>>(
            b1, ll2, lh2, hl2, hh2, ll3, lh3, hl3, hh3, wl, bar, bar + 1);

        idwt2d<<<9 * 9 * 256, 256, 0, stream>>>(
            b1, b1 + N1, b1 + 2 * N1, b1 + 3 * N1, H, pwb + (size_t)l * 32,
            S1, S1, Hp, Hp, (l < 3) ? 1 : 0, 9);
    }

    head_k<<<(8 * 256 * 256 / 2 + 255) / 256, 256, 0, stream>>>(H, fc1w, fc1b, fc2w, fc2b, out);
}

// Round 12
// 1013.260 us; speedup vs baseline: 3.6160x; 3.6160x over previous
//
#include <hip/hip_runtime.h>
#include <math.h>

// ---------------- wavelet filter constants (orthogonal, L=12) ----------------
#define W0f  (-0.00107730108499558f)
#define W1f  (0.004777257511010651f)
#define W2f  (0.0005538422009938016f)
#define W3f  (-0.031582039318031156f)
#define W4f  (0.02752286553001629f)
#define W5f  (0.09750160558707936f)
#define W6f  (-0.12976686756709563f)
#define W7f  (-0.22626469396516913f)
#define W8f  (0.3152503517092432f)
#define W9f  (0.7511339080215775f)
#define W10f (0.4946238903983854f)
#define W11f (0.11154074335008017f)

__constant__ float cKA0[12] = {W11f,W10f,W9f,W8f,W7f,W6f,W5f,W4f,W3f,W2f,W1f,W0f};
__constant__ float cKA1[12] = {W0f,-W1f,W2f,-W3f,W4f,-W5f,W6f,-W7f,W8f,-W9f,W10f,-W11f};
__constant__ float cKS0[12] = {W0f,W1f,W2f,W3f,W4f,W5f,W6f,W7f,W8f,W9f,W10f,W11f};
__constant__ float cKS1[12] = {-W11f,W10f,-W9f,W8f,-W7f,W6f,-W5f,W4f,-W3f,W2f,-W1f,W0f};

// problem-size constants
#define S1c 134
#define S2c 72
#define S3c 41
#define A3c 1681
#define N1c 4596736UL
#define N2c 1327104UL
#define N3c 430336UL
#define PLc 2480128UL

// fast erf (Abramowitz-Stegun 7.1.26, max abs err 1.5e-7)
__device__ __forceinline__ float gelu_f(float x) {
    float z  = x * 0.70710678118654752440f;
    float az = fabsf(z);
    float t  = __builtin_amdgcn_rcpf(1.0f + 0.3275911f * az);
    float p  = t * (0.254829592f + t * (-0.284496736f + t * (1.421413741f +
               t * (-1.453152027f + t * 1.061405429f))));
    float e  = __expf(-az * az);
    float er = copysignf(1.0f - p * e, z);
    return 0.5f * x * (1.0f + er);
}

__device__ __forceinline__ int xcd_swizzle() {
    int bid = blockIdx.x;
    return (bid & 7) * ((int)gridDim.x >> 3) + (bid >> 3);
}

// ---------------- fused 2D analysis DWT: b64 LDS reads + transposed row-pass ----------------
__global__ __launch_bounds__(256) void dwt2d(
    const float* __restrict__ in, float* __restrict__ ll, float* __restrict__ lh,
    float* __restrict__ hl, float* __restrict__ hh, int H, int W, int Ho, int Wo,
    int tilesX) {
    int wg  = xcd_swizzle();
    int tpc = tilesX * tilesX;
    int c   = wg / tpc, rem = wg % tpc;
    int ty0 = (rem / tilesX) * 16;
    int tx0 = (rem % tilesX) * 16;
    const float* img = in + (size_t)c * H * W;
    __shared__ float sIn[42][44];    // even stride: float2-aligned
    __shared__ float rloT[16][44];   // transposed row-pass result [j][r]
    __shared__ float rhiT[16][44];
    int tid = threadIdx.x;
    for (int idx = tid; idx < 42 * 42; idx += 256) {
        int r = idx / 42, q = idx % 42;
        int gy = 2 * ty0 - 10 + r;
        int gx = 2 * tx0 - 10 + q;
        gy = gy < 0 ? -1 - gy : (gy >= H ? 2 * H - 1 - gy : gy);
        gx = gx < 0 ? -1 - gx : (gx >= W ? 2 * W - 1 - gx : gx);
        sIn[r][q] = img[gy * W + gx];
    }
    __syncthreads();
    for (int idx = tid; idx < 42 * 16; idx += 256) {
        int r = idx >> 4, j = idx & 15;
        const float2* s2 = (const float2*)&sIn[r][2 * j];
        float alo = 0.f, ahi = 0.f;
        #pragma unroll
        for (int k = 0; k < 6; k++) {
            float2 v = s2[k];
            alo += v.x * cKA0[2*k] + v.y * cKA0[2*k+1];
            ahi += v.x * cKA1[2*k] + v.y * cKA1[2*k+1];
        }
        rloT[j][r] = alo; rhiT[j][r] = ahi;
    }
    __syncthreads();
    int jy = tid >> 4, jx = tid & 15;
    int oy = ty0 + jy, ox = tx0 + jx;
    if (oy < Ho && ox < Wo) {
        const float2* l2 = (const float2*)&rloT[jx][2 * jy];
        const float2* h2 = (const float2*)&rhiT[jx][2 * jy];
        float a0 = 0.f, a1 = 0.f, a2 = 0.f, a3 = 0.f;
        #pragma unroll
        for (int k = 0; k < 6; k++) {
            float2 vl = l2[k], vh = h2[k];
            a0 += vl.x * cKA0[2*k] + vl.y * cKA0[2*k+1];
            a1 += vl.x * cKA1[2*k] + vl.y * cKA1[2*k+1];
            a2 += vh.x * cKA0[2*k] + vh.y * cKA0[2*k+1];
            a3 += vh.x * cKA1[2*k] + vh.y * cKA1[2*k+1];
        }
        size_t o = (size_t)c * Ho * Wo + (size_t)oy * Wo + ox;
        ll[o] = a0; lh[o] = a1; hl[o] = a2; hh[o] = a3;
    }
}

// ---------------- layer-0 DWT L1 with fc0 + reflect-pad fused in ----------------
__global__ __launch_bounds__(256) void dwt2d_fc0(
    const float* __restrict__ u, const float* __restrict__ par,
    const float* __restrict__ xg, const float* __restrict__ yg,
    const float* __restrict__ fw, const float* __restrict__ fb,
    float* __restrict__ ll, float* __restrict__ lh,
    float* __restrict__ hl, float* __restrict__ hh) {
    const int Hd = 258, S = 256, Ho = S1c, Wo = S1c, tilesX = 9;
    int wg  = xcd_swizzle();
    int tpc = tilesX * tilesX;
    int c   = wg / tpc, rem = wg % tpc;
    int b   = c >> 5, o = c & 31;
    int ty0 = (rem / tilesX) * 16;
    int tx0 = (rem % tilesX) * 16;
    float w0 = fw[o*4], w1 = fw[o*4+1], w2 = fw[o*4+2], w3 = fw[o*4+3], bv = fb[o];
    __shared__ float sIn[42][44];
    __shared__ float rloT[16][44];
    __shared__ float rhiT[16][44];
    int tid = threadIdx.x;
    for (int idx = tid; idx < 42 * 42; idx += 256) {
        int r = idx / 42, q = idx % 42;
        int gy = 2 * ty0 - 10 + r;
        int gx = 2 * tx0 - 10 + q;
        gy = gy < 0 ? -1 - gy : (gy >= Hd ? 2 * Hd - 1 - gy : gy);
        gx = gx < 0 ? -1 - gx : (gx >= Hd ? 2 * Hd - 1 - gx : gx);
        int iy = gy - 1; iy = iy < 0 ? -iy : (iy >= S ? 2 * S - 2 - iy : iy);
        int ix = gx - 1; ix = ix < 0 ? -ix : (ix >= S ? 2 * S - 2 - ix : ix);
        float vu = u  [(b * S + iy) * S + ix];
        float vp = par[(b * S + iy) * S + ix];
        sIn[r][q] = w0 * vu + w1 * vp + w2 * xg[b * S + iy] + w3 * yg[b * S + ix] + bv;
    }
    __syncthreads();
    for (int idx = tid; idx < 42 * 16; idx += 256) {
        int r = idx >> 4, j = idx & 15;
        const float2* s2 = (const float2*)&sIn[r][2 * j];
        float alo = 0.f, ahi = 0.f;
        #pragma unroll
        for (int k = 0; k < 6; k++) {
            float2 v = s2[k];
            alo += v.x * cKA0[2*k] + v.y * cKA0[2*k+1];
            ahi += v.x * cKA1[2*k] + v.y * cKA1[2*k+1];
        }
        rloT[j][r] = alo; rhiT[j][r] = ahi;
    }
    __syncthreads();
    int jy = tid >> 4, jx = tid & 15;
    int oy = ty0 + jy, ox = tx0 + jx;
    if (oy < Ho && ox < Wo) {
        const float2* l2 = (const float2*)&rloT[jx][2 * jy];
        const float2* h2 = (const float2*)&rhiT[jx][2 * jy];
        float a0 = 0.f, a1 = 0.f, a2 = 0.f, a3 = 0.f;
        #pragma unroll
        for (int k = 0; k < 6; k++) {
            float2 vl = l2[k], vh = h2[k];
            a0 += vl.x * cKA0[2*k] + vl.y * cKA0[2*k+1];
            a1 += vl.x * cKA1[2*k] + vl.y * cKA1[2*k+1];
            a2 += vh.x * cKA0[2*k] + vh.y * cKA0[2*k+1];
            a3 += vh.x * cKA1[2*k] + vh.y * cKA1[2*k+1];
        }
        size_t oo = (size_t)c * Ho * Wo + (size_t)oy * Wo + ox;
        ll[oo] = a0; lh[oo] = a1; hl[oo] = a2; hh[oo] = a3;
    }
}

// ---------------- fused 2D synthesis IDWT: paired polyphase (2x fewer LDS reads) ----------------
__global__ __launch_bounds__(256) void idwt2d(
    const float* __restrict__ ll, const float* __restrict__ lh,
    const float* __restrict__ hl, const float* __restrict__ hh,
    float* __restrict__ out, const float* __restrict__ pb,
    int h, int w, int Oh, int Ow, int do_gelu, int tilesX) {
    int wg  = xcd_swizzle();
    int tpc = tilesX * tilesX;
    int c   = wg / tpc, rem = wg % tpc;
    int my0 = (rem / tilesX) * 16;
    int nx0 = (rem % tilesX) * 16;
    __shared__ float sll[21][22], slh[21][22], shl[21][22], shh[21][22];
    __shared__ float sxl[32][23], sxh[32][23];
    int tid = threadIdx.x;
    size_t cb = (size_t)c * h * w;
    float bias = pb ? pb[c & 31] : 0.f;
    for (int idx = tid; idx < 21 * 21; idx += 256) {
        int r = idx / 21, q = idx % 21;
        int gy = min(my0 + r, h - 1);
        int gx = min(nx0 + q, w - 1);
        size_t g = cb + (size_t)gy * w + gx;
        sll[r][q] = ll[g]; slh[r][q] = lh[g];
        shl[r][q] = hl[g]; shh[r][q] = hh[g];
    }
    __syncthreads();
    // height synthesis: item (mp,q) -> rows 2mp, 2mp+1 from one set of band reads
    for (int idx = tid; idx < 16 * 21; idx += 256) {
        int mp = idx / 21, q = idx % 21;
        float al0 = 0.f, al1 = 0.f, ah0 = 0.f, ah1 = 0.f;
        #pragma unroll
        for (int s = 0; s < 6; s++) {
            float vll = sll[mp + s][q], vlh = slh[mp + s][q];
            float vhl = shl[mp + s][q], vhh = shh[mp + s][q];
            float k1f = cKS0[2*s+1], g1f = cKS1[2*s+1];   // p=0
            float k0f = cKS0[2*s],   g0f = cKS1[2*s];     // p=1
            al0 += vll * k1f + vlh * g1f;
            al1 += vll * k0f + vlh * g0f;
            ah0 += vhl * k1f + vhh * g1f;
            ah1 += vhl * k0f + vhh * g0f;
        }
        sxl[2*mp  ][q] = al0; sxh[2*mp  ][q] = ah0;
        sxl[2*mp+1][q] = al1; sxh[2*mp+1][q] = ah1;
    }
    __syncthreads();
    // width synthesis: item (r,np) -> cols 2np, 2np+1; float2 global store
    for (int idx = tid; idx < 32 * 16; idx += 256) {
        int r = idx >> 4, np = idx & 15;
        int oy = 2 * my0 + r, ox = 2 * nx0 + 2 * np;
        if (oy < Oh && ox < Ow) {
            float a0 = bias, a1 = bias;
            #pragma unroll
            for (int s = 0; s < 6; s++) {
                float vl = sxl[r][np + s], vh = sxh[r][np + s];
                a0 += vl * cKS0[2*s+1] + vh * cKS1[2*s+1];   // q=0
                a1 += vl * cKS0[2*s]   + vh * cKS1[2*s];     // q=1
            }
            if (do_gelu) { a0 = gelu_f(a0); a1 = gelu_f(a1); }
            *(float2*)&out[(size_t)c * Oh * Ow + (size_t)oy * Ow + ox] =
                make_float2(a0, a1);
        }
    }
}

// ---------------- transpose all 4 layers ----------------
__global__ __launch_bounds__(256) void transpose_all(
    const float* __restrict__ w, float* __restrict__ wT) {
    __shared__ float t[64][65];
    int l  = blockIdx.y >> 4;
    int by = (blockIdx.y & 15) * 64;
    int bx = blockIdx.x * 64;
    const float* wl = w  + (size_t)l * 4194304;
    float* wTl      = wT + (size_t)l * 4194304;
    int tid = threadIdx.x;
    for (int idx = tid; idx < 4096; idx += 256) {
        int r = idx >> 6, q = idx & 63;
        t[r][q] = wl[(size_t)(by + r) * 4096 + bx + q];
    }
    __syncthreads();
    for (int idx = tid; idx < 4096; idx += 256) {
        int r = idx >> 6, q = idx & 63;
        wTl[(size_t)(bx + r) * 1024 + by + q] = t[q][r];
    }
}

// ---------------- bilinear interp of weights for all 4 layers, + pw folded in ----------------
__global__ __launch_bounds__(256) void interp4(
    const float* __restrict__ wT, const float* __restrict__ pw,
    float* __restrict__ wout) {
    int l = blockIdx.y;
    const float* wTl = wT + (size_t)l * 4194304;
    const float* pwl = pw + (size_t)l * 1024;
    float* base = wout + (size_t)l * PLc;
    __shared__ float spw[1024];
    int tid = threadIdx.x;
    for (int k = tid; k < 1024; k += 256) spw[k] = pwl[(k & 31) * 32 + (k >> 5)];
    __syncthreads();
    int bId = blockIdx.x;
    float* dst; int Ho, Wo, p;
    if (bId < A3c)                          { dst = base;                                  Ho = S3c; Wo = S3c; p = bId; }
    else if (bId < A3c + 3 * S1c)           { dst = base + A3c * 1024;                     Ho = 3;   Wo = S1c; p = bId - A3c; }
    else if (bId < A3c + 3 * (S1c + S2c))   { dst = base + (A3c + 3 * S1c) * 1024;         Ho = 3;   Wo = S2c; p = bId - A3c - 3 * S1c; }
    else                                    { dst = base + (A3c + 3 * (S1c + S2c)) * 1024; Ho = 3;   Wo = S3c; p = bId - A3c - 3 * (S1c + S2c); }
    int y = p / Wo, x = p % Wo;
    float sy = fmaxf((y + 0.5f) * (64.0f / Ho) - 0.5f, 0.0f);
    int y0 = min((int)sy, 63), y1 = min(y0 + 1, 63);
    float ty = fminf(sy - (float)y0, 1.0f);
    float sx = fmaxf((x + 0.5f) * (64.0f / Wo) - 0.5f, 0.0f);
    int x0 = min((int)sx, 63), x1 = min(x0 + 1, 63);
    float tx = fminf(sx - (float)x0, 1.0f);
    float c00 = (1.f - ty) * (1.f - tx), c01 = (1.f - ty) * tx;
    float c10 = ty * (1.f - tx),         c11 = ty * tx;
    const float4* s00 = (const float4*)(wTl + (size_t)(y0 * 64 + x0) * 1024);
    const float4* s01 = (const float4*)(wTl + (size_t)(y0 * 64 + x1) * 1024);
    const float4* s10 = (const float4*)(wTl + (size_t)(y1 * 64 + x0) * 1024);
    const float4* s11 = (const float4*)(wTl + (size_t)(y1 * 64 + x1) * 1024);
    float4* op = (float4*)(dst + (size_t)p * 1024);
    int k = tid;
    float4 a = s00[k], b = s01[k], c = s10[k], d = s11[k];
    float4 pw4 = *(const float4*)&spw[k * 4];
    float4 r;
    r.x = c00*a.x + c01*b.x + c10*c.x + c11*d.x + pw4.x;
    r.y = c00*a.y + c01*b.y + c10*c.y + c11*d.y + pw4.y;
    r.z = c00*a.z + c01*b.z + c10*c.z + c11*d.z + pw4.z;
    r.w = c00*a.w + c01*b.w + c10*c.w + c11*d.w + pw4.w;
    op[k] = r;
}

// ---------------- ALL subband channel mixes for one layer, one dispatch ----------------
__global__ __launch_bounds__(256) void mix_all(
    float* __restrict__ ll3, float* __restrict__ lh3,
    float* __restrict__ lh2, float* __restrict__ lh1,
    const float* __restrict__ wl) {
    const float* wll = wl;
    const float* wh1 = wl + A3c * 1024;
    const float* wh2 = wh1 + 3 * S1c * 1024;
    const float* wh3 = wh2 + 3 * S2c * 1024;
    __shared__ float sw[1024];
    __shared__ float sv[256];
    int tid = threadIdx.x;
    int bid = blockIdx.x;
    if (bid < A3c) {
        const float* wb = wll + (size_t)bid * 1024;
        for (int k = tid; k < 1024; k += 256) sw[k] = wb[k];
        int b = tid >> 5, i = tid & 31;
        sv[tid] = ll3[((size_t)(b * 32 + i)) * A3c + bid];
        __syncthreads();
        float acc = 0.f;
        #pragma unroll
        for (int k = 0; k < 32; k++) acc += sv[b * 32 + k] * sw[k * 32 + i];
        ll3[((size_t)(b * 32 + i)) * A3c + bid] = acc;
        return;
    }
    int t = bid - A3c;
    float* hb; const float* wb; int Hs, Ws, s, y, xb; size_t bstride;
    if (t < 2 * S3c * 3) {
        Hs = Ws = S3c; bstride = N3c;
        int per = 2 * S3c; s = t / per; int r = t % per; y = r / 2; xb = r % 2;
        hb = lh3; wb = wh3;
    } else if ((t -= 2 * S3c * 3) < 3 * S2c * 3) {
        Hs = Ws = S2c; bstride = N2c;
        int per = 3 * S2c; s = t / per; int r = t % per; y = r / 3; xb = r % 3;
        hb = lh2; wb = wh2;
    } else {
        t -= 3 * S2c * 3;
        Hs = Ws = S1c; bstride = N1c;
        int per = 5 * S1c; s = t / per; int r = t % per; y = r / 5; xb = r % 5;
        hb = lh1; wb = wh1;
    }
    hb += (size_t)s * bstride;
    wb += ((size_t)s * Hs + y) * 1024;
    for (int k = tid; k < 1024; k += 256) sw[k] = wb[k];
    __syncthreads();
    int q = xb * 256 + tid;
    if (q >= 8 * Ws) return;
    int b = q / Ws, x = q % Ws;
    size_t base = ((size_t)(b * 32) * Hs + y) * Ws + x;
    size_t cs = (size_t)Hs * Ws;
    float acc[32];
    #pragma unroll
    for (int o = 0; o < 32; o++) acc[o] = 0.f;
    for (int i = 0; i < 32; i++) {
        float v = hb[base + (size_t)i * cs];
        #pragma unroll
        for (int o4 = 0; o4 < 8; o4++) {
            float4 w4 = *(const float4*)&sw[i * 32 + o4 * 4];
            acc[o4*4+0] += v * w4.x; acc[o4*4+1] += v * w4.y;
            acc[o4*4+2] += v * w4.z; acc[o4*4+3] += v * w4.w;
        }
    }
    #pragma unroll
    for (int o = 0; o < 32; o++) hb[base + (size_t)o * cs] = acc[o];
}

// ---------------- head: crop + fc1 + gelu + fc2, 2 px/thread, LDS weights ----------------
__global__ __launch_bounds__(256) void head_k(
    const float* __restrict__ h, const float* __restrict__ w1, const float* __restrict__ b1,
    const float* __restrict__ w2, const float* __restrict__ b2, float* __restrict__ out) {
    __shared__ float sw1[4096];
    __shared__ float sb1[128];
    __shared__ float sw2[128];
    int tid = threadIdx.x;
    for (int k = tid; k < 4096; k += 256) sw1[k] = w1[k];
    if (tid < 128) { sb1[tid] = b1[tid]; sw2[tid] = w2[tid]; }
    __syncthreads();
    const int Hp = 258;
    const int QP = 262144;
    int g0 = blockIdx.x * 256 + tid;
    float in[2][32];
    #pragma unroll
    for (int p = 0; p < 2; p++) {
        int gid = g0 + p * QP;
        int b = gid >> 16, r = gid & 65535;
        int yy = r >> 8, xx = r & 255;
        size_t base = (size_t)b * 32 * Hp * Hp + (size_t)(yy + 1) * Hp + (xx + 1);
        #pragma unroll
        for (int i = 0; i < 32; i++) in[p][i] = h[base + (size_t)i * Hp * Hp];
    }
    float acc0 = 0.f, acc1 = 0.f;
    for (int j = 0; j < 128; j++) {
        float h0 = sb1[j], h1 = h0;
        #pragma unroll
        for (int i4 = 0; i4 < 8; i4++) {
            float4 wv = *(const float4*)&sw1[j * 32 + i4 * 4];
            h0 += wv.x * in[0][i4*4+0] + wv.y * in[0][i4*4+1] + wv.z * in[0][i4*4+2] + wv.w * in[0][i4*4+3];
            h1 += wv.x * in[1][i4*4+0] + wv.y * in[1][i4*4+1] + wv.z * in[1][i4*4+2] + wv.w * in[1][i4*4+3];
        }
        float w2j = sw2[j];
        acc0 += w2j * gelu_f(h0);
        acc1 += w2j * gelu_f(h1);
    }
    float b2v = b2[0];
    out[g0     ] = acc0 + b2v;
    out[g0 + QP] = acc1 + b2v;
}

extern "C" void kernel_launch(void* const* d_in, const int* in_sizes, int n_in,
                              void* d_out, int out_size, void* d_ws, size_t ws_size,
                              hipStream_t stream) {
    (void)in_sizes; (void)n_in; (void)out_size;
    const float* u    = (const float*)d_in[0];
    const float* par  = (const float*)d_in[1];
    const float* xg   = (const float*)d_in[2];
    const float* yg   = (const float*)d_in[3];
    const float* fc0w = (const float*)d_in[4];
    const float* fc0b = (const float*)d_in[5];
    const float* wcw  = (const float*)d_in[6];
    const float* pww  = (const float*)d_in[7];
    const float* pwb  = (const float*)d_in[8];
    const float* fc1w = (const float*)d_in[9];
    const float* fc1b = (const float*)d_in[10];
    const float* fc2w = (const float*)d_in[11];
    const float* fc2b = (const float*)d_in[12];
    float* out = (float*)d_out;
    float* ws  = (float*)d_ws;

    const int Hp = 258;
    const size_t HW = (size_t)Hp * Hp;
    const size_t NH = 256 * HW;
    const int S1 = S1c, S2 = S2c, S3 = S3c;
    const size_t N1 = N1c, N2 = N2c, N3 = N3c;

    float* H   = ws;
    float* ll1 = H   + NH;
    float* lh1 = ll1 + N1;
    float* hl1 = lh1 + N1;
    float* hh1 = hl1 + N1;
    float* ll2 = hh1 + N1;
    float* lh2 = ll2 + N2;
    float* hl2 = lh2 + N2;
    float* hh2 = hl2 + N2;
    float* ll3 = hh2 + N2;
    float* lh3 = ll3 + N3;
    float* hl3 = lh3 + N3;
    float* hh3 = hl3 + N3;
    float* w4  = hh3 + N3;
    size_t needed = (size_t)(w4 + 4 * PLc - ws) * sizeof(float);
    if (ws_size < needed) return;
    float* wTall = lh1;   // overlay (dead until dwt L1 writes it)

    // ---- upfront weight prep ----
    transpose_all<<<dim3(64, 64), 256, 0, stream>>>(wcw, wTall);
    int nInterp = A3c + 3 * (S1 + S2 + S3);
    interp4<<<dim3(nInterp, 4), 256, 0, stream>>>(wTall, pww, w4);

    const int nMix = A3c + 2 * S3 * 3 + 3 * S2 * 3 + 5 * S1 * 3; // 4585

    for (int l = 0; l < 4; l++) {
        const float* wl = w4 + (size_t)l * PLc;

        if (l == 0) {
            dwt2d_fc0<<<9 * 9 * 256, 256, 0, stream>>>(
                u, par, xg, yg, fc0w, fc0b, ll1, lh1, hl1, hh1);
        } else {
            dwt2d<<<9 * 9 * 256, 256, 0, stream>>>(
                H, ll1, lh1, hl1, hh1, Hp, Hp, S1, S1, 9);
        }
        dwt2d<<<5 * 5 * 256, 256, 0, stream>>>(
            ll1, ll2, lh2, hl2, hh2, S1, S1, S2, S2, 5);
        dwt2d<<<3 * 3 * 256, 256, 0, stream>>>(
            ll2, ll3, lh3, hl3, hh3, S2, S2, S3, S3, 3);

        mix_all<<<nMix, 256, 0, stream>>>(ll3, lh3, lh2, lh1, wl);

        idwt2d<<<3 * 3 * 256, 256, 0, stream>>>(
            ll3, lh3, hl3, hh3, ll2, nullptr, S3, S3, S2, S2, 0, 3);
        idwt2d<<<5 * 5 * 256, 256, 0, stream>>>(
            ll2, lh2, hl2, hh2, ll1, nullptr, S2, S2, S1, S1, 0, 5);
        idwt2d<<<9 * 9 * 256, 256, 0, stream>>>(
            ll1, lh1, hl1, hh1, H, pwb + (size_t)l * 32, S1, S1, Hp, Hp,
            (l < 3) ? 1 : 0, 9);
    }

    head_k<<<(8 * 256 * 256 / 2 + 255) / 256, 256, 0, stream>>>(H, fc1w, fc1b, fc2w, fc2b, out);
}

// Round 13
// 954.975 us; speedup vs baseline: 3.8367x; 1.0610x over previous
//
#include <hip/hip_runtime.h>
#include <math.h>

// ---------------- wavelet filter constants (orthogonal, L=12) ----------------
#define W0f  (-0.00107730108499558f)
#define W1f  (0.004777257511010651f)
#define W2f  (0.0005538422009938016f)
#define W3f  (-0.031582039318031156f)
#define W4f  (0.02752286553001629f)
#define W5f  (0.09750160558707936f)
#define W6f  (-0.12976686756709563f)
#define W7f  (-0.22626469396516913f)
#define W8f  (0.3152503517092432f)
#define W9f  (0.7511339080215775f)
#define W10f (0.4946238903983854f)
#define W11f (0.11154074335008017f)

__constant__ float cKA0[12] = {W11f,W10f,W9f,W8f,W7f,W6f,W5f,W4f,W3f,W2f,W1f,W0f};
__constant__ float cKA1[12] = {W0f,-W1f,W2f,-W3f,W4f,-W5f,W6f,-W7f,W8f,-W9f,W10f,-W11f};
__constant__ float cKS0[12] = {W0f,W1f,W2f,W3f,W4f,W5f,W6f,W7f,W8f,W9f,W10f,W11f};
__constant__ float cKS1[12] = {-W11f,W10f,-W9f,W8f,-W7f,W6f,-W5f,W4f,-W3f,W2f,-W1f,W0f};

// problem-size constants
#define S1c 134
#define S2c 72
#define S3c 41
#define A3c 1681
#define N1c 4596736UL
#define N2c 1327104UL
#define N3c 430336UL
#define PLc 2480128UL

// fast erf (Abramowitz-Stegun 7.1.26, max abs err 1.5e-7)
__device__ __forceinline__ float gelu_f(float x) {
    float z  = x * 0.70710678118654752440f;
    float az = fabsf(z);
    float t  = __builtin_amdgcn_rcpf(1.0f + 0.3275911f * az);
    float p  = t * (0.254829592f + t * (-0.284496736f + t * (1.421413741f +
               t * (-1.453152027f + t * 1.061405429f))));
    float e  = __expf(-az * az);
    float er = copysignf(1.0f - p * e, z);
    return 0.5f * x * (1.0f + er);
}

__device__ __forceinline__ int xcd_swizzle() {
    int bid = blockIdx.x;
    return (bid & 7) * ((int)gridDim.x >> 3) + (bid >> 3);
}

// ---- shared dwt passes (after sIn is staged): paired-output, b64 reads ----
__device__ __forceinline__ void dwt_passes(
    float (*sIn)[44], float (*rloT)[44], float (*rhiT)[44],
    float* __restrict__ ll, float* __restrict__ lh,
    float* __restrict__ hl, float* __restrict__ hh,
    int c, int ty0, int tx0, int Ho, int Wo) {
    int tid = threadIdx.x;
    __syncthreads();
    // row pass: item (r, j') -> outputs j=2j', 2j'+1 from one 14-float window
    for (int idx = tid; idx < 42 * 8; idx += 256) {
        int r = idx >> 3, jp = idx & 7;
        const float2* s2 = (const float2*)&sIn[r][4 * jp];
        float v[14];
        #pragma unroll
        for (int k = 0; k < 7; k++) { float2 w = s2[k]; v[2*k] = w.x; v[2*k+1] = w.y; }
        float alo0 = 0.f, ahi0 = 0.f, alo1 = 0.f, ahi1 = 0.f;
        #pragma unroll
        for (int t = 0; t < 12; t++) {
            alo0 += v[t]     * cKA0[t];
            ahi0 += v[t]     * cKA1[t];
            alo1 += v[t + 2] * cKA0[t];
            ahi1 += v[t + 2] * cKA1[t];
        }
        rloT[2*jp  ][r] = alo0; rhiT[2*jp  ][r] = ahi0;
        rloT[2*jp+1][r] = alo1; rhiT[2*jp+1][r] = ahi1;
    }
    __syncthreads();
    // col pass: 256 items: half(lo/hi) x 8 jy' x 16 jx -> 2 rows x 2 outputs
    int half = tid >> 7;
    int rem  = tid & 127;
    int jyp  = rem >> 4, jx = rem & 15;
    const float2* s2 = (const float2*)((half ? &rhiT[jx][0] : &rloT[jx][0]) + 4 * jyp);
    float v[14];
    #pragma unroll
    for (int k = 0; k < 7; k++) { float2 w = s2[k]; v[2*k] = w.x; v[2*k+1] = w.y; }
    float a00 = 0.f, a10 = 0.f, a01 = 0.f, a11 = 0.f;
    #pragma unroll
    for (int t = 0; t < 12; t++) {
        a00 += v[t]     * cKA0[t];
        a10 += v[t]     * cKA1[t];
        a01 += v[t + 2] * cKA0[t];
        a11 += v[t + 2] * cKA1[t];
    }
    float* outA = half ? hl : ll;
    float* outB = half ? hh : lh;
    int oy0 = ty0 + 2 * jyp, ox = tx0 + jx;
    if (ox < Wo) {
        size_t cb = (size_t)c * Ho * Wo + ox;
        if (oy0 < Ho) {
            outA[cb + (size_t)oy0 * Wo] = a00;
            outB[cb + (size_t)oy0 * Wo] = a10;
        }
        if (oy0 + 1 < Ho) {
            outA[cb + (size_t)(oy0 + 1) * Wo] = a01;
            outB[cb + (size_t)(oy0 + 1) * Wo] = a11;
        }
    }
}

// ---------------- fused 2D analysis DWT ----------------
__global__ __launch_bounds__(256) void dwt2d(
    const float* __restrict__ in, float* __restrict__ ll, float* __restrict__ lh,
    float* __restrict__ hl, float* __restrict__ hh, int H, int W, int Ho, int Wo,
    int tilesX) {
    int wg  = xcd_swizzle();
    int tpc = tilesX * tilesX;
    int c   = wg / tpc, rem = wg % tpc;
    int ty0 = (rem / tilesX) * 16;
    int tx0 = (rem % tilesX) * 16;
    const float* img = in + (size_t)c * H * W;
    __shared__ float sIn[42][44];
    __shared__ float rloT[16][44];
    __shared__ float rhiT[16][44];
    int tid = threadIdx.x;
    // stage: 42 rows x 21 col-pairs, float2 LDS writes
    for (int idx = tid; idx < 42 * 21; idx += 256) {
        int r = idx / 21, qp = idx % 21;
        int q0 = 2 * qp;
        int gy = 2 * ty0 - 10 + r;
        gy = gy < 0 ? -1 - gy : (gy >= H ? 2 * H - 1 - gy : gy);
        int gxa = 2 * tx0 - 10 + q0;
        int gxb = gxa + 1;
        gxa = gxa < 0 ? -1 - gxa : (gxa >= W ? 2 * W - 1 - gxa : gxa);
        gxb = gxb < 0 ? -1 - gxb : (gxb >= W ? 2 * W - 1 - gxb : gxb);
        const float* row = img + (size_t)gy * W;
        *(float2*)&sIn[r][q0] = make_float2(row[gxa], row[gxb]);
    }
    dwt_passes(sIn, rloT, rhiT, ll, lh, hl, hh, c, ty0, tx0, Ho, Wo);
}

// ---------------- layer-0 DWT L1 with fc0 + reflect-pad fused in ----------------
__global__ __launch_bounds__(256) void dwt2d_fc0(
    const float* __restrict__ u, const float* __restrict__ par,
    const float* __restrict__ xg, const float* __restrict__ yg,
    const float* __restrict__ fw, const float* __restrict__ fb,
    float* __restrict__ ll, float* __restrict__ lh,
    float* __restrict__ hl, float* __restrict__ hh) {
    const int Hd = 258, S = 256, Ho = S1c, Wo = S1c, tilesX = 9;
    int wg  = xcd_swizzle();
    int tpc = tilesX * tilesX;
    int c   = wg / tpc, rem = wg % tpc;
    int b   = c >> 5, o = c & 31;
    int ty0 = (rem / tilesX) * 16;
    int tx0 = (rem % tilesX) * 16;
    float w0 = fw[o*4], w1 = fw[o*4+1], w2 = fw[o*4+2], w3 = fw[o*4+3], bv = fb[o];
    __shared__ float sIn[42][44];
    __shared__ float rloT[16][44];
    __shared__ float rhiT[16][44];
    int tid = threadIdx.x;
    for (int idx = tid; idx < 42 * 21; idx += 256) {
        int r = idx / 21, qp = idx % 21;
        int q0 = 2 * qp;
        int gy = 2 * ty0 - 10 + r;
        gy = gy < 0 ? -1 - gy : (gy >= Hd ? 2 * Hd - 1 - gy : gy);
        int iy = gy - 1; iy = iy < 0 ? -iy : (iy >= S ? 2 * S - 2 - iy : iy);
        float xv = xg[b * S + iy];
        float res[2];
        #pragma unroll
        for (int e = 0; e < 2; e++) {
            int gx = 2 * tx0 - 10 + q0 + e;
            gx = gx < 0 ? -1 - gx : (gx >= Hd ? 2 * Hd - 1 - gx : gx);
            int ix = gx - 1; ix = ix < 0 ? -ix : (ix >= S ? 2 * S - 2 - ix : ix);
            float vu = u  [(b * S + iy) * S + ix];
            float vp = par[(b * S + iy) * S + ix];
            res[e] = w0 * vu + w1 * vp + w2 * xv + w3 * yg[b * S + ix] + bv;
        }
        *(float2*)&sIn[r][q0] = make_float2(res[0], res[1]);
    }
    dwt_passes(sIn, rloT, rhiT, ll, lh, hl, hh, c, ty0, tx0, Ho, Wo);
}

// ---------------- fused 2D synthesis IDWT: paired polyphase both axes ----------------
__global__ __launch_bounds__(256) void idwt2d(
    const float* __restrict__ ll, const float* __restrict__ lh,
    const float* __restrict__ hl, const float* __restrict__ hh,
    float* __restrict__ out, const float* __restrict__ pb,
    int h, int w, int Oh, int Ow, int do_gelu, int tilesX) {
    int wg  = xcd_swizzle();
    int tpc = tilesX * tilesX;
    int c   = wg / tpc, rem = wg % tpc;
    int my0 = (rem / tilesX) * 16;
    int nx0 = (rem % tilesX) * 16;
    __shared__ float sll[21][22], slh[21][22], shl[21][22], shh[21][22];
    __shared__ float sxl[32][24], sxh[32][24];
    int tid = threadIdx.x;
    size_t cb = (size_t)c * h * w;
    float bias = pb ? pb[c & 31] : 0.f;
    for (int idx = tid; idx < 21 * 21; idx += 256) {
        int r = idx / 21, q = idx % 21;
        int gy = min(my0 + r, h - 1);
        int gx = min(nx0 + q, w - 1);
        size_t g = cb + (size_t)gy * w + gx;
        sll[r][q] = ll[g]; slh[r][q] = lh[g];
        shl[r][q] = hl[g]; shh[r][q] = hh[g];
    }
    __syncthreads();
    // height synthesis: item (half, mp2, q): 7 band rows -> 4 output rows
    for (int idx = tid; idx < 336; idx += 256) {
        int half = idx / 168, r2 = idx % 168;
        int mp2 = r2 / 21, q = r2 % 21;
        float (*A)[22] = half ? shl : sll;
        float (*B)[22] = half ? shh : slh;
        float (*X)[24] = half ? sxh : sxl;
        float av[7], bv2[7];
        #pragma unroll
        for (int rr = 0; rr < 7; rr++) {
            av[rr]  = A[2 * mp2 + rr][q];
            bv2[rr] = B[2 * mp2 + rr][q];
        }
        float r0 = 0.f, r1 = 0.f, r2v = 0.f, r3 = 0.f;
        #pragma unroll
        for (int s = 0; s < 6; s++) {
            float k1f = cKS0[2*s+1], g1f = cKS1[2*s+1];
            float k0f = cKS0[2*s],   g0f = cKS1[2*s];
            r0  += av[s]   * k1f + bv2[s]   * g1f;
            r1  += av[s]   * k0f + bv2[s]   * g0f;
            r2v += av[s+1] * k1f + bv2[s+1] * g1f;
            r3  += av[s+1] * k0f + bv2[s+1] * g0f;
        }
        X[4*mp2  ][q] = r0;  X[4*mp2+1][q] = r1;
        X[4*mp2+2][q] = r2v; X[4*mp2+3][q] = r3;
    }
    __syncthreads();
    // width synthesis: 256 items (r, np2): 8 floats each of sxl/sxh -> 4 outputs
    {
        int r = tid >> 3, np2 = tid & 7;
        const float2* l2 = (const float2*)&sxl[r][2 * np2];
        const float2* h2 = (const float2*)&sxh[r][2 * np2];
        float lv[8], hv[8];
        #pragma unroll
        for (int k = 0; k < 4; k++) {
            float2 a = l2[k], bq = h2[k];
            lv[2*k] = a.x; lv[2*k+1] = a.y;
            hv[2*k] = bq.x; hv[2*k+1] = bq.y;
        }
        float a00 = bias, a01 = bias, a10 = bias, a11 = bias;
        #pragma unroll
        for (int s = 0; s < 6; s++) {
            float k1f = cKS0[2*s+1], g1f = cKS1[2*s+1];
            float k0f = cKS0[2*s],   g0f = cKS1[2*s];
            a00 += lv[s]   * k1f + hv[s]   * g1f;
            a01 += lv[s]   * k0f + hv[s]   * g0f;
            a10 += lv[s+1] * k1f + hv[s+1] * g1f;
            a11 += lv[s+1] * k0f + hv[s+1] * g0f;
        }
        int oy = 2 * my0 + r;
        int ox = 2 * nx0 + 4 * np2;
        if (oy < Oh) {
            if (do_gelu) { a00 = gelu_f(a00); a01 = gelu_f(a01); a10 = gelu_f(a10); a11 = gelu_f(a11); }
            size_t ob = (size_t)c * Oh * Ow + (size_t)oy * Ow;
            if (ox < Ow)     *(float2*)&out[ob + ox]     = make_float2(a00, a01);
            if (ox + 2 < Ow) *(float2*)&out[ob + ox + 2] = make_float2(a10, a11);
        }
    }
}

// ---------------- transpose all 4 layers ----------------
__global__ __launch_bounds__(256) void transpose_all(
    const float* __restrict__ w, float* __restrict__ wT) {
    __shared__ float t[64][65];
    int l  = blockIdx.y >> 4;
    int by = (blockIdx.y & 15) * 64;
    int bx = blockIdx.x * 64;
    const float* wl = w  + (size_t)l * 4194304;
    float* wTl      = wT + (size_t)l * 4194304;
    int tid = threadIdx.x;
    for (int idx = tid; idx < 4096; idx += 256) {
        int r = idx >> 6, q = idx & 63;
        t[r][q] = wl[(size_t)(by + r) * 4096 + bx + q];
    }
    __syncthreads();
    for (int idx = tid; idx < 4096; idx += 256) {
        int r = idx >> 6, q = idx & 63;
        wTl[(size_t)(bx + r) * 1024 + by + q] = t[q][r];
    }
}

// ---------------- bilinear interp of weights for all 4 layers, + pw folded in ----------------
__global__ __launch_bounds__(256) void interp4(
    const float* __restrict__ wT, const float* __restrict__ pw,
    float* __restrict__ wout) {
    int l = blockIdx.y;
    const float* wTl = wT + (size_t)l * 4194304;
    const float* pwl = pw + (size_t)l * 1024;
    float* base = wout + (size_t)l * PLc;
    __shared__ float spw[1024];
    int tid = threadIdx.x;
    for (int k = tid; k < 1024; k += 256) spw[k] = pwl[(k & 31) * 32 + (k >> 5)];
    __syncthreads();
    int bId = blockIdx.x;
    float* dst; int Ho, Wo, p;
    if (bId < A3c)                          { dst = base;                                  Ho = S3c; Wo = S3c; p = bId; }
    else if (bId < A3c + 3 * S1c)           { dst = base + A3c * 1024;                     Ho = 3;   Wo = S1c; p = bId - A3c; }
    else if (bId < A3c + 3 * (S1c + S2c))   { dst = base + (A3c + 3 * S1c) * 1024;         Ho = 3;   Wo = S2c; p = bId - A3c - 3 * S1c; }
    else                                    { dst = base + (A3c + 3 * (S1c + S2c)) * 1024; Ho = 3;   Wo = S3c; p = bId - A3c - 3 * (S1c + S2c); }
    int y = p / Wo, x = p % Wo;
    float sy = fmaxf((y + 0.5f) * (64.0f / Ho) - 0.5f, 0.0f);
    int y0 = min((int)sy, 63), y1 = min(y0 + 1, 63);
    float ty = fminf(sy - (float)y0, 1.0f);
    float sx = fmaxf((x + 0.5f) * (64.0f / Wo) - 0.5f, 0.0f);
    int x0 = min((int)sx, 63), x1 = min(x0 + 1, 63);
    float tx = fminf(sx - (float)x0, 1.0f);
    float c00 = (1.f - ty) * (1.f - tx), c01 = (1.f - ty) * tx;
    float c10 = ty * (1.f - tx),         c11 = ty * tx;
    const float4* s00 = (const float4*)(wTl + (size_t)(y0 * 64 + x0) * 1024);
    const float4* s01 = (const float4*)(wTl + (size_t)(y0 * 64 + x1) * 1024);
    const float4* s10 = (const float4*)(wTl + (size_t)(y1 * 64 + x0) * 1024);
    const float4* s11 = (const float4*)(wTl + (size_t)(y1 * 64 + x1) * 1024);
    float4* op = (float4*)(dst + (size_t)p * 1024);
    int k = tid;
    float4 a = s00[k], b = s01[k], c = s10[k], d = s11[k];
    float4 pw4 = *(const float4*)&spw[k * 4];
    float4 r;
    r.x = c00*a.x + c01*b.x + c10*c.x + c11*d.x + pw4.x;
    r.y = c00*a.y + c01*b.y + c10*c.y + c11*d.y + pw4.y;
    r.z = c00*a.z + c01*b.z + c10*c.z + c11*d.z + pw4.z;
    r.w = c00*a.w + c01*b.w + c10*c.w + c11*d.w + pw4.w;
    op[k] = r;
}

// ---------------- ALL subband channel mixes for one layer, one dispatch ----------------
__global__ __launch_bounds__(256) void mix_all(
    float* __restrict__ ll3, float* __restrict__ lh3,
    float* __restrict__ lh2, float* __restrict__ lh1,
    const float* __restrict__ wl) {
    const float* wll = wl;
    const float* wh1 = wl + A3c * 1024;
    const float* wh2 = wh1 + 3 * S1c * 1024;
    const float* wh3 = wh2 + 3 * S2c * 1024;
    __shared__ float sw[1024];
    __shared__ float sv[256];
    int tid = threadIdx.x;
    int bid = blockIdx.x;
    if (bid < A3c) {
        const float* wb = wll + (size_t)bid * 1024;
        for (int k = tid; k < 1024; k += 256) sw[k] = wb[k];
        int b = tid >> 5, i = tid & 31;
        sv[tid] = ll3[((size_t)(b * 32 + i)) * A3c + bid];
        __syncthreads();
        float acc = 0.f;
        #pragma unroll
        for (int k = 0; k < 32; k++) acc += sv[b * 32 + k] * sw[k * 32 + i];
        ll3[((size_t)(b * 32 + i)) * A3c + bid] = acc;
        return;
    }
    int t = bid - A3c;
    float* hb; const float* wb; int Hs, Ws, s, y, xb; size_t bstride;
    if (t < 2 * S3c * 3) {
        Hs = Ws = S3c; bstride = N3c;
        int per = 2 * S3c; s = t / per; int r = t % per; y = r / 2; xb = r % 2;
        hb = lh3; wb = wh3;
    } else if ((t -= 2 * S3c * 3) < 3 * S2c * 3) {
        Hs = Ws = S2c; bstride = N2c;
        int per = 3 * S2c; s = t / per; int r = t % per; y = r / 3; xb = r % 3;
        hb = lh2; wb = wh2;
    } else {
        t -= 3 * S2c * 3;
        Hs = Ws = S1c; bstride = N1c;
        int per = 5 * S1c; s = t / per; int r = t % per; y = r / 5; xb = r % 5;
        hb = lh1; wb = wh1;
    }
    hb += (size_t)s * bstride;
    wb += ((size_t)s * Hs + y) * 1024;
    for (int k = tid; k < 1024; k += 256) sw[k] = wb[k];
    __syncthreads();
    int q = xb * 256 + tid;
    if (q >= 8 * Ws) return;
    int b = q / Ws, x = q % Ws;
    size_t base = ((size_t)(b * 32) * Hs + y) * Ws + x;
    size_t cs = (size_t)Hs * Ws;
    float acc[32];
    #pragma unroll
    for (int o = 0; o < 32; o++) acc[o] = 0.f;
    for (int i = 0; i < 32; i++) {
        float v = hb[base + (size_t)i * cs];
        #pragma unroll
        for (int o4 = 0; o4 < 8; o4++) {
            float4 w4 = *(const float4*)&sw[i * 32 + o4 * 4];
            acc[o4*4+0] += v * w4.x; acc[o4*4+1] += v * w4.y;
            acc[o4*4+2] += v * w4.z; acc[o4*4+3] += v * w4.w;
        }
    }
    #pragma unroll
    for (int o = 0; o < 32; o++) hb[base + (size_t)o * cs] = acc[o];
}

// ---------------- head: crop + fc1 + gelu + fc2, 2 px/thread, LDS weights ----------------
__global__ __launch_bounds__(256) void head_k(
    const float* __restrict__ h, const float* __restrict__ w1, const float* __restrict__ b1,
    const float* __restrict__ w2, const float* __restrict__ b2, float* __restrict__ out) {
    __shared__ float sw1[4096];
    __shared__ float sb1[128];
    __shared__ float sw2[128];
    int tid = threadIdx.x;
    for (int k = tid; k < 4096; k += 256) sw1[k] = w1[k];
    if (tid < 128) { sb1[tid] = b1[tid]; sw2[tid] = w2[tid]; }
    __syncthreads();
    const int Hp = 258;
    const int QP = 262144;
    int g0 = blockIdx.x * 256 + tid;
    float in[2][32];
    #pragma unroll
    for (int p = 0; p < 2; p++) {
        int gid = g0 + p * QP;
        int b = gid >> 16, r = gid & 65535;
        int yy = r >> 8, xx = r & 255;
        size_t base = (size_t)b * 32 * Hp * Hp + (size_t)(yy + 1) * Hp + (xx + 1);
        #pragma unroll
        for (int i = 0; i < 32; i++) in[p][i] = h[base + (size_t)i * Hp * Hp];
    }
    float acc0 = 0.f, acc1 = 0.f;
    for (int j = 0; j < 128; j++) {
        float h0 = sb1[j], h1 = h0;
        #pragma unroll
        for (int i4 = 0; i4 < 8; i4++) {
            float4 wv = *(const float4*)&sw1[j * 32 + i4 * 4];
            h0 += wv.x * in[0][i4*4+0] + wv.y * in[0][i4*4+1] + wv.z * in[0][i4*4+2] + wv.w * in[0][i4*4+3];
            h1 += wv.x * in[1][i4*4+0] + wv.y * in[1][i4*4+1] + wv.z * in[1][i4*4+2] + wv.w * in[1][i4*4+3];
        }
        float w2j = sw2[j];
        acc0 += w2j * gelu_f(h0);
        acc1 += w2j * gelu_f(h1);
    }
    float b2v = b2[0];
    out[g0     ] = acc0 + b2v;
    out[g0 + QP] = acc1 + b2v;
}

extern "C" void kernel_launch(void* const* d_in, const int* in_sizes, int n_in,
                              void* d_out, int out_size, void* d_ws, size_t ws_size,
                              hipStream_t stream) {
    (void)in_sizes; (void)n_in; (void)out_size;
    const float* u    = (const float*)d_in[0];
    const float* par  = (const float*)d_in[1];
    const float* xg   = (const float*)d_in[2];
    const float* yg   = (const float*)d_in[3];
    const float* fc0w = (const float*)d_in[4];
    const float* fc0b = (const float*)d_in[5];
    const float* wcw  = (const float*)d_in[6];
    const float* pww  = (const float*)d_in[7];
    const float* pwb  = (const float*)d_in[8];
    const float* fc1w = (const float*)d_in[9];
    const float* fc1b = (const float*)d_in[10];
    const float* fc2w = (const float*)d_in[11];
    const float* fc2b = (const float*)d_in[12];
    float* out = (float*)d_out;
    float* ws  = (float*)d_ws;

    const int Hp = 258;
    const size_t HW = (size_t)Hp * Hp;
    const size_t NH = 256 * HW;
    const int S1 = S1c, S2 = S2c, S3 = S3c;
    const size_t N1 = N1c, N2 = N2c, N3 = N3c;

    float* H   = ws;
    float* ll1 = H   + NH;
    float* lh1 = ll1 + N1;
    float* hl1 = lh1 + N1;
    float* hh1 = hl1 + N1;
    float* ll2 = hh1 + N1;
    float* lh2 = ll2 + N2;
    float* hl2 = lh2 + N2;
    float* hh2 = hl2 + N2;
    float* ll3 = hh2 + N2;
    float* lh3 = ll3 + N3;
    float* hl3 = lh3 + N3;
    float* hh3 = hl3 + N3;
    float* w4  = hh3 + N3;
    size_t needed = (size_t)(w4 + 4 * PLc - ws) * sizeof(float);
    if (ws_size < needed) return;
    float* wTall = lh1;   // overlay (dead until dwt L1 writes it)

    // ---- upfront weight prep ----
    transpose_all<<<dim3(64, 64), 256, 0, stream>>>(wcw, wTall);
    int nInterp = A3c + 3 * (S1 + S2 + S3);
    interp4<<<dim3(nInterp, 4), 256, 0, stream>>>(wTall, pww, w4);

    const int nMix = A3c + 2 * S3 * 3 + 3 * S2 * 3 + 5 * S1 * 3; // 4585

    for (int l = 0; l < 4; l++) {
        const float* wl = w4 + (size_t)l * PLc;

        if (l == 0) {
            dwt2d_fc0<<<9 * 9 * 256, 256, 0, stream>>>(
                u, par, xg, yg, fc0w, fc0b, ll1, lh1, hl1, hh1);
        } else {
            dwt2d<<<9 * 9 * 256, 256, 0, stream>>>(
                H, ll1, lh1, hl1, hh1, Hp, Hp, S1, S1, 9);
        }
        dwt2d<<<5 * 5 * 256, 256, 0, stream>>>(
            ll1, ll2, lh2, hl2, hh2, S1, S1, S2, S2, 5);
        dwt2d<<<3 * 3 * 256, 256, 0, stream>>>(
            ll2, ll3, lh3, hl3, hh3, S2, S2, S3, S3, 3);

        mix_all<<<nMix, 256, 0, stream>>>(ll3, lh3, lh2, lh1, wl);

        idwt2d<<<3 * 3 * 256, 256, 0, stream>>>(
            ll3, lh3, hl3, hh3, ll2, nullptr, S3, S3, S2, S2, 0, 3);
        idwt2d<<<5 * 5 * 256, 256, 0, stream>>>(
            ll2, lh2, hl2, hh2, ll1, nullptr, S2, S2, S1, S1, 0, 5);
        idwt2d<<<9 * 9 * 256, 256, 0, stream>>>(
            ll1, lh1, hl1, hh1, H, pwb + (size_t)l * 32, S1, S1, Hp, Hp,
            (l < 3) ? 1 : 0, 9);
    }

    head_k<<<(8 * 256 * 256 / 2 + 255) / 256, 256, 0, stream>>>(H, fc1w, fc1b, fc2w, fc2b, out);
}

// Round 14
// 951.448 us; speedup vs baseline: 3.8509x; 1.0037x over previous
//
#include <hip/hip_runtime.h>
#include <math.h>

// ---------------- wavelet filter constants (orthogonal, L=12) ----------------
#define W0f  (-0.00107730108499558f)
#define W1f  (0.004777257511010651f)
#define W2f  (0.0005538422009938016f)
#define W3f  (-0.031582039318031156f)
#define W4f  (0.02752286553001629f)
#define W5f  (0.09750160558707936f)
#define W6f  (-0.12976686756709563f)
#define W7f  (-0.22626469396516913f)
#define W8f  (0.3152503517092432f)
#define W9f  (0.7511339080215775f)
#define W10f (0.4946238903983854f)
#define W11f (0.11154074335008017f)

__constant__ float cKA0[12] = {W11f,W10f,W9f,W8f,W7f,W6f,W5f,W4f,W3f,W2f,W1f,W0f};
__constant__ float cKA1[12] = {W0f,-W1f,W2f,-W3f,W4f,-W5f,W6f,-W7f,W8f,-W9f,W10f,-W11f};
__constant__ float cKS0[12] = {W0f,W1f,W2f,W3f,W4f,W5f,W6f,W7f,W8f,W9f,W10f,W11f};
__constant__ float cKS1[12] = {-W11f,W10f,-W9f,W8f,-W7f,W6f,-W5f,W4f,-W3f,W2f,-W1f,W0f};

// problem-size constants
#define S1c 134
#define S2c 72
#define S3c 41
#define A3c 1681
#define N1c 4596736UL
#define N2c 1327104UL
#define N3c 430336UL
#define PLc 2480128UL

// fast erf (Abramowitz-Stegun 7.1.26, max abs err 1.5e-7)
__device__ __forceinline__ float gelu_f(float x) {
    float z  = x * 0.70710678118654752440f;
    float az = fabsf(z);
    float t  = __builtin_amdgcn_rcpf(1.0f + 0.3275911f * az);
    float p  = t * (0.254829592f + t * (-0.284496736f + t * (1.421413741f +
               t * (-1.453152027f + t * 1.061405429f))));
    float e  = __expf(-az * az);
    float er = copysignf(1.0f - p * e, z);
    return 0.5f * x * (1.0f + er);
}

__device__ __forceinline__ int xcd_swizzle() {
    int bid = blockIdx.x;
    return (bid & 7) * ((int)gridDim.x >> 3) + (bid >> 3);
}

// ---- shared dwt passes (after sIn is staged): paired-output, b64 reads ----
__device__ __forceinline__ void dwt_passes(
    float (*sIn)[44], float (*rloT)[44], float (*rhiT)[44],
    float* __restrict__ ll, float* __restrict__ lh,
    float* __restrict__ hl, float* __restrict__ hh,
    int c, int ty0, int tx0, int Ho, int Wo) {
    int tid = threadIdx.x;
    __syncthreads();
    // row pass: item (r, j') -> outputs j=2j', 2j'+1 from one 14-float window
    for (int idx = tid; idx < 42 * 8; idx += 256) {
        int r = idx >> 3, jp = idx & 7;
        const float2* s2 = (const float2*)&sIn[r][4 * jp];
        float v[14];
        #pragma unroll
        for (int k = 0; k < 7; k++) { float2 w = s2[k]; v[2*k] = w.x; v[2*k+1] = w.y; }
        float alo0 = 0.f, ahi0 = 0.f, alo1 = 0.f, ahi1 = 0.f;
        #pragma unroll
        for (int t = 0; t < 12; t++) {
            alo0 += v[t]     * cKA0[t];
            ahi0 += v[t]     * cKA1[t];
            alo1 += v[t + 2] * cKA0[t];
            ahi1 += v[t + 2] * cKA1[t];
        }
        rloT[2*jp  ][r] = alo0; rhiT[2*jp  ][r] = ahi0;
        rloT[2*jp+1][r] = alo1; rhiT[2*jp+1][r] = ahi1;
    }
    __syncthreads();
    // col pass: 256 items: half(lo/hi) x 8 jy' x 16 jx -> 2 rows x 2 outputs
    int half = tid >> 7;
    int rem  = tid & 127;
    int jyp  = rem >> 4, jx = rem & 15;
    const float2* s2 = (const float2*)((half ? &rhiT[jx][0] : &rloT[jx][0]) + 4 * jyp);
    float v[14];
    #pragma unroll
    for (int k = 0; k < 7; k++) { float2 w = s2[k]; v[2*k] = w.x; v[2*k+1] = w.y; }
    float a00 = 0.f, a10 = 0.f, a01 = 0.f, a11 = 0.f;
    #pragma unroll
    for (int t = 0; t < 12; t++) {
        a00 += v[t]     * cKA0[t];
        a10 += v[t]     * cKA1[t];
        a01 += v[t + 2] * cKA0[t];
        a11 += v[t + 2] * cKA1[t];
    }
    float* outA = half ? hl : ll;
    float* outB = half ? hh : lh;
    int oy0 = ty0 + 2 * jyp, ox = tx0 + jx;
    if (ox < Wo) {
        size_t cb = (size_t)c * Ho * Wo + ox;
        if (oy0 < Ho) {
            outA[cb + (size_t)oy0 * Wo] = a00;
            outB[cb + (size_t)oy0 * Wo] = a10;
        }
        if (oy0 + 1 < Ho) {
            outA[cb + (size_t)(oy0 + 1) * Wo] = a01;
            outB[cb + (size_t)(oy0 + 1) * Wo] = a11;
        }
    }
}

// ---------------- fused 2D analysis DWT ----------------
__global__ __launch_bounds__(256) void dwt2d(
    const float* __restrict__ in, float* __restrict__ ll, float* __restrict__ lh,
    float* __restrict__ hl, float* __restrict__ hh, int H, int W, int Ho, int Wo,
    int tilesX) {
    int wg  = xcd_swizzle();
    int tpc = tilesX * tilesX;
    int c   = wg / tpc, rem = wg % tpc;
    int ty0 = (rem / tilesX) * 16;
    int tx0 = (rem % tilesX) * 16;
    const float* img = in + (size_t)c * H * W;
    __shared__ float sIn[42][44];
    __shared__ float rloT[16][44];
    __shared__ float rhiT[16][44];
    int tid = threadIdx.x;
    // stage: 42 rows x 21 col-pairs, float2 LDS writes
    for (int idx = tid; idx < 42 * 21; idx += 256) {
        int r = idx / 21, qp = idx % 21;
        int q0 = 2 * qp;
        int gy = 2 * ty0 - 10 + r;
        gy = gy < 0 ? -1 - gy : (gy >= H ? 2 * H - 1 - gy : gy);
        int gxa = 2 * tx0 - 10 + q0;
        int gxb = gxa + 1;
        gxa = gxa < 0 ? -1 - gxa : (gxa >= W ? 2 * W - 1 - gxa : gxa);
        gxb = gxb < 0 ? -1 - gxb : (gxb >= W ? 2 * W - 1 - gxb : gxb);
        const float* row = img + (size_t)gy * W;
        *(float2*)&sIn[r][q0] = make_float2(row[gxa], row[gxb]);
    }
    dwt_passes(sIn, rloT, rhiT, ll, lh, hl, hh, c, ty0, tx0, Ho, Wo);
}

// ---------------- layer-0 DWT L1 with fc0 + reflect-pad fused in ----------------
__global__ __launch_bounds__(256) void dwt2d_fc0(
    const float* __restrict__ u, const float* __restrict__ par,
    const float* __restrict__ xg, const float* __restrict__ yg,
    const float* __restrict__ fw, const float* __restrict__ fb,
    float* __restrict__ ll, float* __restrict__ lh,
    float* __restrict__ hl, float* __restrict__ hh) {
    const int Hd = 258, S = 256, Ho = S1c, Wo = S1c, tilesX = 9;
    int wg  = xcd_swizzle();
    int tpc = tilesX * tilesX;
    int c   = wg / tpc, rem = wg % tpc;
    int b   = c >> 5, o = c & 31;
    int ty0 = (rem / tilesX) * 16;
    int tx0 = (rem % tilesX) * 16;
    float w0 = fw[o*4], w1 = fw[o*4+1], w2 = fw[o*4+2], w3 = fw[o*4+3], bv = fb[o];
    __shared__ float sIn[42][44];
    __shared__ float rloT[16][44];
    __shared__ float rhiT[16][44];
    int tid = threadIdx.x;
    for (int idx = tid; idx < 42 * 21; idx += 256) {
        int r = idx / 21, qp = idx % 21;
        int q0 = 2 * qp;
        int gy = 2 * ty0 - 10 + r;
        gy = gy < 0 ? -1 - gy : (gy >= Hd ? 2 * Hd - 1 - gy : gy);
        int iy = gy - 1; iy = iy < 0 ? -iy : (iy >= S ? 2 * S - 2 - iy : iy);
        float xv = xg[b * S + iy];
        float res[2];
        #pragma unroll
        for (int e = 0; e < 2; e++) {
            int gx = 2 * tx0 - 10 + q0 + e;
            gx = gx < 0 ? -1 - gx : (gx >= Hd ? 2 * Hd - 1 - gx : gx);
            int ix = gx - 1; ix = ix < 0 ? -ix : (ix >= S ? 2 * S - 2 - ix : ix);
            float vu = u  [(b * S + iy) * S + ix];
            float vp = par[(b * S + iy) * S + ix];
            res[e] = w0 * vu + w1 * vp + w2 * xv + w3 * yg[b * S + ix] + bv;
        }
        *(float2*)&sIn[r][q0] = make_float2(res[0], res[1]);
    }
    dwt_passes(sIn, rloT, rhiT, ll, lh, hl, hh, c, ty0, tx0, Ho, Wo);
}

// ---------------- fused 2D synthesis IDWT: paired polyphase both axes ----------------
__global__ __launch_bounds__(256) void idwt2d(
    const float* __restrict__ ll, const float* __restrict__ lh,
    const float* __restrict__ hl, const float* __restrict__ hh,
    float* __restrict__ out, const float* __restrict__ pb,
    int h, int w, int Oh, int Ow, int do_gelu, int tilesX) {
    int wg  = xcd_swizzle();
    int tpc = tilesX * tilesX;
    int c   = wg / tpc, rem = wg % tpc;
    int my0 = (rem / tilesX) * 16;
    int nx0 = (rem % tilesX) * 16;
    __shared__ float sll[21][22], slh[21][22], shl[21][22], shh[21][22];
    __shared__ float sxl[32][24], sxh[32][24];
    int tid = threadIdx.x;
    size_t cb = (size_t)c * h * w;
    float bias = pb ? pb[c & 31] : 0.f;
    for (int idx = tid; idx < 21 * 21; idx += 256) {
        int r = idx / 21, q = idx % 21;
        int gy = min(my0 + r, h - 1);
        int gx = min(nx0 + q, w - 1);
        size_t g = cb + (size_t)gy * w + gx;
        sll[r][q] = ll[g]; slh[r][q] = lh[g];
        shl[r][q] = hl[g]; shh[r][q] = hh[g];
    }
    __syncthreads();
    // height synthesis: item (half, mp2, q): 7 band rows -> 4 output rows
    for (int idx = tid; idx < 336; idx += 256) {
        int half = idx / 168, r2 = idx % 168;
        int mp2 = r2 / 21, q = r2 % 21;
        float (*A)[22] = half ? shl : sll;
        float (*B)[22] = half ? shh : slh;
        float (*X)[24] = half ? sxh : sxl;
        float av[7], bv2[7];
        #pragma unroll
        for (int rr = 0; rr < 7; rr++) {
            av[rr]  = A[2 * mp2 + rr][q];
            bv2[rr] = B[2 * mp2 + rr][q];
        }
        float r0 = 0.f, r1 = 0.f, r2v = 0.f, r3 = 0.f;
        #pragma unroll
        for (int s = 0; s < 6; s++) {
            float k1f = cKS0[2*s+1], g1f = cKS1[2*s+1];
            float k0f = cKS0[2*s],   g0f = cKS1[2*s];
            r0  += av[s]   * k1f + bv2[s]   * g1f;
            r1  += av[s]   * k0f + bv2[s]   * g0f;
            r2v += av[s+1] * k1f + bv2[s+1] * g1f;
            r3  += av[s+1] * k0f + bv2[s+1] * g0f;
        }
        X[4*mp2  ][q] = r0;  X[4*mp2+1][q] = r1;
        X[4*mp2+2][q] = r2v; X[4*mp2+3][q] = r3;
    }
    __syncthreads();
    // width synthesis: 256 items (r, np2): 8 floats each of sxl/sxh -> 4 outputs
    {
        int r = tid >> 3, np2 = tid & 7;
        const float2* l2 = (const float2*)&sxl[r][2 * np2];
        const float2* h2 = (const float2*)&sxh[r][2 * np2];
        float lv[8], hv[8];
        #pragma unroll
        for (int k = 0; k < 4; k++) {
            float2 a = l2[k], bq = h2[k];
            lv[2*k] = a.x; lv[2*k+1] = a.y;
            hv[2*k] = bq.x; hv[2*k+1] = bq.y;
        }
        float a00 = bias, a01 = bias, a10 = bias, a11 = bias;
        #pragma unroll
        for (int s = 0; s < 6; s++) {
            float k1f = cKS0[2*s+1], g1f = cKS1[2*s+1];
            float k0f = cKS0[2*s],   g0f = cKS1[2*s];
            a00 += lv[s]   * k1f + hv[s]   * g1f;
            a01 += lv[s]   * k0f + hv[s]   * g0f;
            a10 += lv[s+1] * k1f + hv[s+1] * g1f;
            a11 += lv[s+1] * k0f + hv[s+1] * g0f;
        }
        int oy = 2 * my0 + r;
        int ox = 2 * nx0 + 4 * np2;
        if (oy < Oh) {
            if (do_gelu) { a00 = gelu_f(a00); a01 = gelu_f(a01); a10 = gelu_f(a10); a11 = gelu_f(a11); }
            size_t ob = (size_t)c * Oh * Ow + (size_t)oy * Ow;
            if (ox < Ow)     *(float2*)&out[ob + ox]     = make_float2(a00, a01);
            if (ox + 2 < Ow) *(float2*)&out[ob + ox + 2] = make_float2(a10, a11);
        }
    }
}

// ---------------- transpose all 4 layers ----------------
__global__ __launch_bounds__(256) void transpose_all(
    const float* __restrict__ w, float* __restrict__ wT) {
    __shared__ float t[64][65];
    int l  = blockIdx.y >> 4;
    int by = (blockIdx.y & 15) * 64;
    int bx = blockIdx.x * 64;
    const float* wl = w  + (size_t)l * 4194304;
    float* wTl      = wT + (size_t)l * 4194304;
    int tid = threadIdx.x;
    for (int idx = tid; idx < 4096; idx += 256) {
        int r = idx >> 6, q = idx & 63;
        t[r][q] = wl[(size_t)(by + r) * 4096 + bx + q];
    }
    __syncthreads();
    for (int idx = tid; idx < 4096; idx += 256) {
        int r = idx >> 6, q = idx & 63;
        wTl[(size_t)(bx + r) * 1024 + by + q] = t[q][r];
    }
}

// ---------------- bilinear interp of weights for all 4 layers, + pw folded in ----------------
__global__ __launch_bounds__(256) void interp4(
    const float* __restrict__ wT, const float* __restrict__ pw,
    float* __restrict__ wout) {
    int l = blockIdx.y;
    const float* wTl = wT + (size_t)l * 4194304;
    const float* pwl = pw + (size_t)l * 1024;
    float* base = wout + (size_t)l * PLc;
    __shared__ float spw[1024];
    int tid = threadIdx.x;
    for (int k = tid; k < 1024; k += 256) spw[k] = pwl[(k & 31) * 32 + (k >> 5)];
    __syncthreads();
    int bId = blockIdx.x;
    float* dst; int Ho, Wo, p;
    if (bId < A3c)                          { dst = base;                                  Ho = S3c; Wo = S3c; p = bId; }
    else if (bId < A3c + 3 * S1c)           { dst = base + A3c * 1024;                     Ho = 3;   Wo = S1c; p = bId - A3c; }
    else if (bId < A3c + 3 * (S1c + S2c))   { dst = base + (A3c + 3 * S1c) * 1024;         Ho = 3;   Wo = S2c; p = bId - A3c - 3 * S1c; }
    else                                    { dst = base + (A3c + 3 * (S1c + S2c)) * 1024; Ho = 3;   Wo = S3c; p = bId - A3c - 3 * (S1c + S2c); }
    int y = p / Wo, x = p % Wo;
    float sy = fmaxf((y + 0.5f) * (64.0f / Ho) - 0.5f, 0.0f);
    int y0 = min((int)sy, 63), y1 = min(y0 + 1, 63);
    float ty = fminf(sy - (float)y0, 1.0f);
    float sx = fmaxf((x + 0.5f) * (64.0f / Wo) - 0.5f, 0.0f);
    int x0 = min((int)sx, 63), x1 = min(x0 + 1, 63);
    float tx = fminf(sx - (float)x0, 1.0f);
    float c00 = (1.f - ty) * (1.f - tx), c01 = (1.f - ty) * tx;
    float c10 = ty * (1.f - tx),         c11 = ty * tx;
    const float4* s00 = (const float4*)(wTl + (size_t)(y0 * 64 + x0) * 1024);
    const float4* s01 = (const float4*)(wTl + (size_t)(y0 * 64 + x1) * 1024);
    const float4* s10 = (const float4*)(wTl + (size_t)(y1 * 64 + x0) * 1024);
    const float4* s11 = (const float4*)(wTl + (size_t)(y1 * 64 + x1) * 1024);
    float4* op = (float4*)(dst + (size_t)p * 1024);
    int k = tid;
    float4 a = s00[k], b = s01[k], c = s10[k], d = s11[k];
    float4 pw4 = *(const float4*)&spw[k * 4];
    float4 r;
    r.x = c00*a.x + c01*b.x + c10*c.x + c11*d.x + pw4.x;
    r.y = c00*a.y + c01*b.y + c10*c.y + c11*d.y + pw4.y;
    r.z = c00*a.z + c01*b.z + c10*c.z + c11*d.z + pw4.z;
    r.w = c00*a.w + c01*b.w + c10*c.w + c11*d.w + pw4.w;
    op[k] = r;
}

// ---------------- ALL subband channel mixes for one layer, one dispatch ----------------
__global__ __launch_bounds__(256) void mix_all(
    float* __restrict__ ll3, float* __restrict__ lh3,
    float* __restrict__ lh2, float* __restrict__ lh1,
    const float* __restrict__ wl) {
    const float* wll = wl;
    const float* wh1 = wl + A3c * 1024;
    const float* wh2 = wh1 + 3 * S1c * 1024;
    const float* wh3 = wh2 + 3 * S2c * 1024;
    __shared__ float sw[1024];
    __shared__ float sv[256];
    int tid = threadIdx.x;
    int bid = blockIdx.x;
    if (bid < A3c) {
        const float* wb = wll + (size_t)bid * 1024;
        for (int k = tid; k < 1024; k += 256) sw[k] = wb[k];
        int b = tid >> 5, i = tid & 31;
        sv[tid] = ll3[((size_t)(b * 32 + i)) * A3c + bid];
        __syncthreads();
        float acc = 0.f;
        #pragma unroll
        for (int k = 0; k < 32; k++) acc += sv[b * 32 + k] * sw[k * 32 + i];
        ll3[((size_t)(b * 32 + i)) * A3c + bid] = acc;
        return;
    }
    int t = bid - A3c;
    float* hb; const float* wb; int Hs, Ws, s, y, xb; size_t bstride;
    if (t < 2 * S3c * 3) {
        Hs = Ws = S3c; bstride = N3c;
        int per = 2 * S3c; s = t / per; int r = t % per; y = r / 2; xb = r % 2;
        hb = lh3; wb = wh3;
    } else if ((t -= 2 * S3c * 3) < 3 * S2c * 3) {
        Hs = Ws = S2c; bstride = N2c;
        int per = 3 * S2c; s = t / per; int r = t % per; y = r / 3; xb = r % 3;
        hb = lh2; wb = wh2;
    } else {
        t -= 3 * S2c * 3;
        Hs = Ws = S1c; bstride = N1c;
        int per = 5 * S1c; s = t / per; int r = t % per; y = r / 5; xb = r % 5;
        hb = lh1; wb = wh1;
    }
    hb += (size_t)s * bstride;
    wb += ((size_t)s * Hs + y) * 1024;
    for (int k = tid; k < 1024; k += 256) sw[k] = wb[k];
    __syncthreads();
    int q = xb * 256 + tid;
    if (q >= 8 * Ws) return;
    int b = q / Ws, x = q % Ws;
    size_t base = ((size_t)(b * 32) * Hs + y) * Ws + x;
    size_t cs = (size_t)Hs * Ws;
    float acc[32];
    #pragma unroll
    for (int o = 0; o < 32; o++) acc[o] = 0.f;
    for (int i = 0; i < 32; i++) {
        float v = hb[base + (size_t)i * cs];
        #pragma unroll
        for (int o4 = 0; o4 < 8; o4++) {
            float4 w4 = *(const float4*)&sw[i * 32 + o4 * 4];
            acc[o4*4+0] += v * w4.x; acc[o4*4+1] += v * w4.y;
            acc[o4*4+2] += v * w4.z; acc[o4*4+3] += v * w4.w;
        }
    }
    #pragma unroll
    for (int o = 0; o < 32; o++) hb[base + (size_t)o * cs] = acc[o];
}

// ---------------- head: crop + fc1 + gelu + fc2, 2 px/thread, LDS weights ----------------
__global__ __launch_bounds__(256) void head_k(
    const float* __restrict__ h, const float* __restrict__ w1, const float* __restrict__ b1,
    const float* __restrict__ w2, const float* __restrict__ b2, float* __restrict__ out) {
    __shared__ float sw1[4096];
    __shared__ float sb1[128];
    __shared__ float sw2[128];
    int tid = threadIdx.x;
    for (int k = tid; k < 4096; k += 256) sw1[k] = w1[k];
    if (tid < 128) { sb1[tid] = b1[tid]; sw2[tid] = w2[tid]; }
    __syncthreads();
    const int Hp = 258;
    const int QP = 262144;
    int g0 = blockIdx.x * 256 + tid;
    float in[2][32];
    #pragma unroll
    for (int p = 0; p < 2; p++) {
        int gid = g0 + p * QP;
        int b = gid >> 16, r = gid & 65535;
        int yy = r >> 8, xx = r & 255;
        size_t base = (size_t)b * 32 * Hp * Hp + (size_t)(yy + 1) * Hp + (xx + 1);
        #pragma unroll
        for (int i = 0; i < 32; i++) in[p][i] = h[base + (size_t)i * Hp * Hp];
    }
    float acc0 = 0.f, acc1 = 0.f;
    for (int j = 0; j < 128; j++) {
        float h0 = sb1[j], h1 = h0;
        #pragma unroll
        for (int i4 = 0; i4 < 8; i4++) {
            float4 wv = *(const float4*)&sw1[j * 32 + i4 * 4];
            h0 += wv.x * in[0][i4*4+0] + wv.y * in[0][i4*4+1] + wv.z * in[0][i4*4+2] + wv.w * in[0][i4*4+3];
            h1 += wv.x * in[1][i4*4+0] + wv.y * in[1][i4*4+1] + wv.z * in[1][i4*4+2] + wv.w * in[1][i4*4+3];
        }
        float w2j = sw2[j];
        acc0 += w2j * gelu_f(h0);
        acc1 += w2j * gelu_f(h1);
    }
    float b2v = b2[0];
    out[g0     ] = acc0 + b2v;
    out[g0 + QP] = acc1 + b2v;
}

extern "C" void kernel_launch(void* const* d_in, const int* in_sizes, int n_in,
                              void* d_out, int out_size, void* d_ws, size_t ws_size,
                              hipStream_t stream) {
    (void)in_sizes; (void)n_in; (void)out_size;
    const float* u    = (const float*)d_in[0];
    const float* par  = (const float*)d_in[1];
    const float* xg   = (const float*)d_in[2];
    const float* yg   = (const float*)d_in[3];
    const float* fc0w = (const float*)d_in[4];
    const float* fc0b = (const float*)d_in[5];
    const float* wcw  = (const float*)d_in[6];
    const float* pww  = (const float*)d_in[7];
    const float* pwb  = (const float*)d_in[8];
    const float* fc1w = (const float*)d_in[9];
    const float* fc1b = (const float*)d_in[10];
    const float* fc2w = (const float*)d_in[11];
    const float* fc2b = (const float*)d_in[12];
    float* out = (float*)d_out;
    float* ws  = (float*)d_ws;

    const int Hp = 258;
    const size_t HW = (size_t)Hp * Hp;
    const size_t NH = 256 * HW;
    const int S1 = S1c, S2 = S2c, S3 = S3c;
    const size_t N1 = N1c, N2 = N2c, N3 = N3c;

    float* H   = ws;
    float* ll1 = H   + NH;
    float* lh1 = ll1 + N1;
    float* hl1 = lh1 + N1;
    float* hh1 = hl1 + N1;
    float* ll2 = hh1 + N1;
    float* lh2 = ll2 + N2;
    float* hl2 = lh2 + N2;
    float* hh2 = hl2 + N2;
    float* ll3 = hh2 + N2;
    float* lh3 = ll3 + N3;
    float* hl3 = lh3 + N3;
    float* hh3 = hl3 + N3;
    float* w4  = hh3 + N3;
    size_t needed = (size_t)(w4 + 4 * PLc - ws) * sizeof(float);
    if (ws_size < needed) return;
    float* wTall = lh1;   // overlay (dead until dwt L1 writes it)

    // ---- upfront weight prep ----
    transpose_all<<<dim3(64, 64), 256, 0, stream>>>(wcw, wTall);
    int nInterp = A3c + 3 * (S1 + S2 + S3);
    interp4<<<dim3(nInterp, 4), 256, 0, stream>>>(wTall, pww, w4);

    const int nMix = A3c + 2 * S3 * 3 + 3 * S2 * 3 + 5 * S1 * 3; // 4585

    for (int l = 0; l < 4; l++) {
        const float* wl = w4 + (size_t)l * PLc;

        if (l == 0) {
            dwt2d_fc0<<<9 * 9 * 256, 256, 0, stream>>>(
                u, par, xg, yg, fc0w, fc0b, ll1, lh1, hl1, hh1);
        } else {
            dwt2d<<<9 * 9 * 256, 256, 0, stream>>>(
                H, ll1, lh1, hl1, hh1, Hp, Hp, S1, S1, 9);
        }
        dwt2d<<<5 * 5 * 256, 256, 0, stream>>>(
            ll1, ll2, lh2, hl2, hh2, S1, S1, S2, S2, 5);
        dwt2d<<<3 * 3 * 256, 256, 0, stream>>>(
            ll2, ll3, lh3, hl3, hh3, S2, S2, S3, S3, 3);

        mix_all<<<nMix, 256, 0, stream>>>(ll3, lh3, lh2, lh1, wl);

        idwt2d<<<3 * 3 * 256, 256, 0, stream>>>(
            ll3, lh3, hl3, hh3, ll2, nullptr, S3, S3, S2, S2, 0, 3);
        idwt2d<<<5 * 5 * 256, 256, 0, stream>>>(
            ll2, lh2, hl2, hh2, ll1, nullptr, S2, S2, S1, S1, 0, 5);
        idwt2d<<<9 * 9 * 256, 256, 0, stream>>>(
            ll1, lh1, hl1, hh1, H, pwb + (size_t)l * 32, S1, S1, Hp, Hp,
            (l < 3) ? 1 : 0, 9);
    }

    head_k<<<(8 * 256 * 256 / 2 + 255) / 256, 256, 0, stream>>>(H, fc1w, fc1b, fc2w, fc2b, out);
}